// Round 2
// baseline (5210.490 us; speedup 1.0000x reference)
//
#include <hip/hip_runtime.h>
#include <math.h>

#define N_ANCH 76725
#define NMS_CAP 12288

struct TrunkArgs {
  const float* in[2][5];
  float* out[2][5];
  const float* w[2];
  const float* b[2];
};

struct OutArgs {
  const float* in[5];
  const float* w;
  const float* b;
  float* dst;
};

__device__ __forceinline__ int pick5(int l, int a, int b, int c, int d, int e) {
  int r = a;
  if (l == 1) r = b;
  if (l == 2) r = c;
  if (l == 3) r = d;
  if (l == 4) r = e;
  return r;
}

__device__ __forceinline__ void tile_to_level(int tile, int& lvl, int& t) {
  int l = 0;
  if (tile >= 100) l = 1;
  if (tile >= 125) l = 2;
  if (tile >= 134) l = 3;
  if (tile >= 138) l = 4;
  lvl = l;
  t = tile - pick5(l, 0, 100, 125, 134, 138);
}

// ---------------- trunk conv: 256->256, 3x3, SAME, ReLU ----------------
// block tile: 64 positions (8x8 spatial) x 64 output channels, BK=8.
// thread tile: 4 positions (one row) x 4 consecutive co.
__global__ __launch_bounds__(256) void conv_trunk(TrunkArgs args) {
  __shared__ float As[8][10][12];   // [ci][py][px], rows padded to 12 (16B aligned)
  __shared__ float Ws[8][9][68];    // [ci][tap][co], pad 68 breaks bank conflicts, keeps 16B align
  int lvl, t;
  tile_to_level(blockIdx.x, lvl, t);
  const int W = 80 >> lvl;
  const int HW = W * W;
  const int tX = (W + 7) >> 3;
  const int ty0 = (t / tX) * 8, tx0 = (t % tX) * 8;
  const int head = blockIdx.z;
  const int co0 = blockIdx.y << 6;
  const float* __restrict__ in = args.in[head][lvl];
  float* __restrict__ out = args.out[head][lvl];
  const float* __restrict__ wp = args.w[head];
  const int tid = threadIdx.x;
  const int cop = tid & 15, posp = tid >> 4;
  const int py = posp >> 1, px = (posp & 1) << 2;
  const int co_sub = cop << 2;
  float acc[4][4] = {};

  for (int ci0 = 0; ci0 < 256; ci0 += 8) {
    __syncthreads();
    // stage input patch: 8 ci x 10x10 (halo 1, zero pad at borders)
    for (int e = tid; e < 800; e += 256) {
      int ci = e / 100;
      int rem = e - ci * 100;
      int yy = rem / 10;
      int xx = rem - yy * 10;
      int gy = ty0 + yy - 1, gx = tx0 + xx - 1;
      float v = 0.f;
      if ((unsigned)gy < (unsigned)W && (unsigned)gx < (unsigned)W)
        v = in[(ci0 + ci) * HW + gy * W + gx];
      As[ci][yy][xx] = v;
    }
    // stage weights: 64 co x 8 ci x 9 taps (coalesced over [ci][tap] runs of 72)
    const float* wb = wp + (size_t)co0 * 2304 + (size_t)ci0 * 9;
    for (int e = tid; e < 4608; e += 256) {
      int tap = e % 9;
      int ci = (e / 9) & 7;
      int co = e / 72;
      Ws[ci][tap][co] = wb[co * 2304 + ci * 9 + tap];
    }
    __syncthreads();
    #pragma unroll 2
    for (int ci = 0; ci < 8; ci++) {
      #pragma unroll
      for (int ty = 0; ty < 3; ty++) {
        const float* ar = &As[ci][py + ty][px];
        float4 av = *(const float4*)ar;         // aligned: row stride 48B, px in {0,4}
        float2 av2 = *(const float2*)(ar + 4);
        float a[6] = {av.x, av.y, av.z, av.w, av2.x, av2.y};
        #pragma unroll
        for (int tx = 0; tx < 3; tx++) {
          float4 wv = *(const float4*)&Ws[ci][ty * 3 + tx][co_sub];
          #pragma unroll
          for (int p = 0; p < 4; p++) {
            acc[p][0] = fmaf(a[tx + p], wv.x, acc[p][0]);
            acc[p][1] = fmaf(a[tx + p], wv.y, acc[p][1]);
            acc[p][2] = fmaf(a[tx + p], wv.z, acc[p][2]);
            acc[p][3] = fmaf(a[tx + p], wv.w, acc[p][3]);
          }
        }
      }
    }
  }
  const float4 bias = *(const float4*)&args.b[head][co0 + co_sub];
  const int oy = ty0 + py;
  if (oy < W) {
    #pragma unroll
    for (int p = 0; p < 4; p++) {
      int ox = tx0 + px + p;
      if (ox < W) {
        int base = oy * W + ox;
        out[(co0 + co_sub + 0) * HW + base] = fmaxf(acc[p][0] + bias.x, 0.f);
        out[(co0 + co_sub + 1) * HW + base] = fmaxf(acc[p][1] + bias.y, 0.f);
        out[(co0 + co_sub + 2) * HW + base] = fmaxf(acc[p][2] + bias.z, 0.f);
        out[(co0 + co_sub + 3) * HW + base] = fmaxf(acc[p][3] + bias.w, 0.f);
      }
    }
  }
}

// ---------------- output conv: 256 -> CO (9 cls / 36 reg), NHWC scatter ----------------
template <int CO, bool SIG>
__global__ __launch_bounds__(256) void conv_out_k(OutArgs args) {
  __shared__ float As[8][10][12];
  __shared__ float Wo[8][9][CO];
  int lvl, t;
  tile_to_level(blockIdx.x, lvl, t);
  const int W = 80 >> lvl;
  const int HW = W * W;
  const int tX = (W + 7) >> 3;
  const int ty0 = (t / tX) * 8, tx0 = (t % tX) * 8;
  const float* __restrict__ in = args.in[lvl];
  const int tid = threadIdx.x;
  const int pos = tid & 63;
  const int y = pos >> 3, x = pos & 7;
  const int cset = tid >> 6;
  constexpr int NJ = (CO + 3) / 4;
  float acc[NJ] = {};

  for (int ci0 = 0; ci0 < 256; ci0 += 8) {
    __syncthreads();
    for (int e = tid; e < 800; e += 256) {
      int ci = e / 100;
      int rem = e - ci * 100;
      int yy = rem / 10;
      int xx = rem - yy * 10;
      int gy = ty0 + yy - 1, gx = tx0 + xx - 1;
      float v = 0.f;
      if ((unsigned)gy < (unsigned)W && (unsigned)gx < (unsigned)W)
        v = in[(ci0 + ci) * HW + gy * W + gx];
      As[ci][yy][xx] = v;
    }
    for (int e = tid; e < CO * 72; e += 256) {
      int tap = e % 9;
      int ci = (e / 9) & 7;
      int co = e / 72;
      Wo[ci][tap][co] = args.w[co * 2304 + (ci0 + ci) * 9 + tap];
    }
    __syncthreads();
    #pragma unroll 2
    for (int ci = 0; ci < 8; ci++) {
      #pragma unroll
      for (int ty = 0; ty < 3; ty++) {
        float a[3];
        a[0] = As[ci][y + ty][x + 0];
        a[1] = As[ci][y + ty][x + 1];
        a[2] = As[ci][y + ty][x + 2];
        #pragma unroll
        for (int tx = 0; tx < 3; tx++) {
          const float* wr = &Wo[ci][ty * 3 + tx][0];
          #pragma unroll
          for (int j = 0; j < NJ; j++) {
            int co = cset + 4 * j;
            if (co < CO) acc[j] = fmaf(a[tx], wr[co], acc[j]);
          }
        }
      }
    }
  }
  const int oy = ty0 + y, ox = tx0 + x;
  if (oy < W && ox < W) {
    const int cell = oy * W + ox;
    const int aoff = pick5(lvl, 0, 57600, 72000, 75600, 76500) * (CO / 9);
    #pragma unroll
    for (int j = 0; j < NJ; j++) {
      int co = cset + 4 * j;
      if (co < CO) {
        float v = acc[j] + args.b[co];
        if (SIG) v = 1.f / (1.f + expf(-v));
        args.dst[aoff + cell * CO + co] = v;
      }
    }
  }
}

// ---------------- init / decode / NMS ----------------
__global__ void init_k(int* cnt) {
  if (threadIdx.x == 0 && blockIdx.x == 0) *cnt = 0;
}

__global__ __launch_bounds__(256) void decode_k(const float* __restrict__ scores,
                                                const float* __restrict__ regs,
                                                float* cand_s, float4* cand_b,
                                                int* cand_n, int* cnt) {
  int n = blockIdx.x * 256 + threadIdx.x;
  if (n >= N_ANCH) return;
  int lvl = 0;
  if (n >= 57600) lvl = 1;
  if (n >= 72000) lvl = 2;
  if (n >= 75600) lvl = 3;
  if (n >= 76500) lvl = 4;
  const int aoff = pick5(lvl, 0, 57600, 72000, 75600, 76500);
  const int W = 80 >> lvl;
  int r = n - aoff;
  int a = r % 9;
  int cell = r / 9;
  int x = cell % W, y = cell / W;
  // anchors in double, single rounding to f32 (matches numpy build_anchors)
  double stride = (double)(8 << lvl);
  double base = (double)(32 << lvl);
  int si = a % 3, ri = a / 3;
  double s = (si == 0) ? 1.0 : (si == 1) ? 1.2599210498948731648 : 1.5874010519681994748;
  double ratio = (ri == 0) ? 0.5 : (ri == 1) ? 1.0 : 2.0;
  double ws0 = base * s;
  double area = ws0 * ws0;
  double w = sqrt(area / ratio);
  double h = w * ratio;
  double cx = ((double)x + 0.5) * stride;
  double cy = ((double)y + 0.5) * stride;
  float ax1 = (float)(cx - 0.5 * w);
  float ay1 = (float)(cy - 0.5 * h);
  float ax2 = (float)(cx + (w - 0.5 * w));
  float ay2 = (float)(cy + (h - 0.5 * h));
  float4 rg = ((const float4*)regs)[n];
  float aw = ax2 - ax1, ah = ay2 - ay1;
  float acx = ax1 + 0.5f * aw, acy = ay1 + 0.5f * ah;
  float pcx = acx + rg.x * 0.1f * aw;
  float pcy = acy + rg.y * 0.1f * ah;
  float pw = expf(rg.z * 0.2f) * aw;
  float ph = expf(rg.w * 0.2f) * ah;
  float x1 = pcx - 0.5f * pw, y1 = pcy - 0.5f * ph;
  float x2 = pcx + 0.5f * pw, y2 = pcy + 0.5f * ph;
  x1 = fminf(fmaxf(x1, 0.f), 640.f);
  y1 = fminf(fmaxf(y1, 0.f), 640.f);
  x2 = fminf(fmaxf(x2, 0.f), 640.f);
  y2 = fminf(fmaxf(y2, 0.f), 640.f);
  float sc = scores[n];
  if (sc > 0.05f) {
    int p = atomicAdd(cnt, 1);
    cand_s[p] = sc;
    cand_b[p] = make_float4(x1, y1, x2, y2);
    cand_n[p] = n;
  }
}

// greedy NMS, one block, 512 threads (8 waves). Scores cached in LDS
// (suppression = writing -inf to LDS); boxes/ids stay in global (read-only,
// L1/L2 resident). Fused suppress+argmax per iteration; first-index
// tie-break on original anchor id mirrors jnp.argmax.
__global__ __launch_bounds__(512) void nms_k(float* cs, const float4* __restrict__ cb,
                                             const int* __restrict__ cn,
                                             const int* __restrict__ cnt,
                                             float* __restrict__ out) {
  __shared__ float ls[NMS_CAP];   // 48 KB score cache
  __shared__ float rs[8];
  __shared__ int rn[8];
  __shared__ int rj[8];
  __shared__ float sS;
  __shared__ int sJ;
  const int tid = threadIdx.x;
  const int m = min(*cnt, N_ANCH);
  const int mc = min(m, NMS_CAP);
  for (int j = tid; j < mc; j += 512) ls[j] = cs[j];
  __syncthreads();

  float selS = -INFINITY;
  float4 selB = make_float4(0.f, 0.f, 0.f, 0.f);
  float selA = 0.f;

  for (int it = 0; it <= 300; it++) {
    if (it > 0 && tid == 0) {
      int i = it - 1;
      bool keep = selS != -INFINITY;
      out[i] = keep ? selS : 0.f;
      out[300 + i] = keep ? 0.f : -1.f;   // label 0 if kept else -1
      float4 b = keep ? selB : make_float4(0.f, 0.f, 0.f, 0.f);
      out[600 + 4 * i + 0] = b.x;
      out[600 + 4 * i + 1] = b.y;
      out[600 + 4 * i + 2] = b.z;
      out[600 + 4 * i + 3] = b.w;
    }
    if (it == 300) break;
    const bool sup = it > 0;
    float bs = -INFINITY;
    int bn = 0x7fffffff;
    int bj = 0;
    for (int j = tid; j < m; j += 512) {
      float s = (j < NMS_CAP) ? ls[j] : cs[j];
      if (s == -INFINITY) continue;
      if (sup) {
        float4 b = cb[j];
        float xx1 = fmaxf(selB.x, b.x), yy1 = fmaxf(selB.y, b.y);
        float xx2 = fminf(selB.z, b.z), yy2 = fminf(selB.w, b.w);
        float inter = fmaxf(xx2 - xx1, 0.f) * fmaxf(yy2 - yy1, 0.f);
        float ar = (b.z - b.x) * (b.w - b.y);
        float iou = inter / (ar + selA - inter + 1e-8f);
        if (iou > 0.5f) {
          if (j < NMS_CAP) ls[j] = -INFINITY; else cs[j] = -INFINITY;
          continue;
        }
      }
      int n = cn[j];
      if (s > bs || (s == bs && n < bn)) { bs = s; bn = n; bj = j; }
    }
    #pragma unroll
    for (int off = 32; off; off >>= 1) {
      float os = __shfl_down(bs, off);
      int on = __shfl_down(bn, off);
      int oj = __shfl_down(bj, off);
      if (os > bs || (os == bs && on < bn)) { bs = os; bn = on; bj = oj; }
    }
    if ((tid & 63) == 0) {
      int wv = tid >> 6;
      rs[wv] = bs; rn[wv] = bn; rj[wv] = bj;
    }
    __syncthreads();
    if (tid == 0) {
      #pragma unroll
      for (int k = 1; k < 8; k++)
        if (rs[k] > bs || (rs[k] == bs && rn[k] < bn)) { bs = rs[k]; bn = rn[k]; bj = rj[k]; }
      sS = bs; sJ = bj;
    }
    __syncthreads();
    selS = sS;
    if (selS != -INFINITY) selB = cb[sJ];
    else selB = make_float4(0.f, 0.f, 0.f, 0.f);
    selA = (selB.z - selB.x) * (selB.w - selB.y);
  }
}

// ---------------- host ----------------
extern "C" void kernel_launch(void* const* d_in, const int* in_sizes, int n_in,
                              void* d_out, int out_size, void* d_ws, size_t ws_size,
                              hipStream_t stream) {
  (void)in_sizes; (void)n_in; (void)out_size; (void)ws_size;
  const float* feats[5];
  for (int l = 0; l < 5; l++) feats[l] = (const float*)d_in[1 + l];
  const float* cls_w = (const float*)d_in[6];
  const float* cls_b = (const float*)d_in[7];
  const float* cls_ow = (const float*)d_in[8];
  const float* cls_ob = (const float*)d_in[9];
  const float* reg_w = (const float*)d_in[10];
  const float* reg_b = (const float*)d_in[11];
  const float* reg_ow = (const float*)d_in[12];
  const float* reg_ob = (const float*)d_in[13];

  static const int AOFF[5] = {0, 1638400, 2048000, 2150400, 2176000}; // 256*cumHW
  const size_t ACT = 2182400;  // 256*8525 floats per head

  float* ws = (float*)d_ws;
  float* bufA = ws;                       // 2*ACT
  float* bufB = bufA + 2 * ACT;           // 2*ACT
  float* scores = bufB + 2 * ACT;         // 76736 (padded)
  float* regs = scores + 76736;           // 306912 (padded)
  float* cand_s = regs + 306912;          // 76736
  float* cand_b = cand_s + 76736;         // 306944
  int* cand_n = (int*)(cand_b + 306944);  // 76736 ints
  int* cnt = cand_n + 76736;

  float* bufs[2] = {bufA, bufB};
  TrunkArgs ta;
  for (int layer = 0; layer < 4; layer++) {
    for (int h = 0; h < 2; h++) {
      ta.w[h] = (h ? reg_w : cls_w) + (size_t)layer * 589824;
      ta.b[h] = (h ? reg_b : cls_b) + layer * 256;
      for (int l = 0; l < 5; l++) {
        ta.out[h][l] = bufs[layer & 1] + h * ACT + AOFF[l];
        ta.in[h][l] = (layer == 0) ? feats[l] : (const float*)(bufs[(layer - 1) & 1] + h * ACT + AOFF[l]);
      }
    }
    conv_trunk<<<dim3(139, 4, 2), dim3(256), 0, stream>>>(ta);
  }

  OutArgs oc, og;
  for (int l = 0; l < 5; l++) {
    oc.in[l] = bufB + 0 * ACT + AOFF[l];
    og.in[l] = bufB + 1 * ACT + AOFF[l];
  }
  oc.w = cls_ow; oc.b = cls_ob; oc.dst = scores;
  og.w = reg_ow; og.b = reg_ob; og.dst = regs;
  conv_out_k<9, true><<<dim3(139), dim3(256), 0, stream>>>(oc);
  conv_out_k<36, false><<<dim3(139), dim3(256), 0, stream>>>(og);

  init_k<<<1, 64, 0, stream>>>(cnt);
  decode_k<<<dim3((N_ANCH + 255) / 256), dim3(256), 0, stream>>>(scores, regs, cand_s,
                                                                 (float4*)cand_b, cand_n, cnt);
  nms_k<<<1, 1024 / 2, 0, stream>>>(cand_s, (const float4*)cand_b, cand_n, cnt, (float*)d_out);
}

// Round 3
// 2797.062 us; speedup vs baseline: 1.8628x; 1.8628x over previous
//
#include <hip/hip_runtime.h>
#include <math.h>

#define N_ANCH 76725
#define SORT_N 4096
#define NBKT 1024
#define BBASE 0x3D40u

struct TrunkArgs {
  const float* in[2][5];
  float* out[2][5];
  const float* w[2];
  const float* b[2];
};

struct OutArgs {
  const float* in[5];
  const float* w;
  const float* b;
  float* dst;
};

__device__ __forceinline__ int pick5(int l, int a, int b, int c, int d, int e) {
  int r = a;
  if (l == 1) r = b;
  if (l == 2) r = c;
  if (l == 3) r = d;
  if (l == 4) r = e;
  return r;
}

__device__ __forceinline__ void tile_to_level(int tile, int& lvl, int& t) {
  int l = 0;
  if (tile >= 100) l = 1;
  if (tile >= 125) l = 2;
  if (tile >= 134) l = 3;
  if (tile >= 138) l = 4;
  lvl = l;
  t = tile - pick5(l, 0, 100, 125, 134, 138);
}

// ---------------- trunk conv: 256->256, 3x3, SAME, ReLU (unchanged) ----------------
__global__ __launch_bounds__(256) void conv_trunk(TrunkArgs args) {
  __shared__ float As[8][10][12];
  __shared__ float Ws[8][9][68];
  int lvl, t;
  tile_to_level(blockIdx.x, lvl, t);
  const int W = 80 >> lvl;
  const int HW = W * W;
  const int tX = (W + 7) >> 3;
  const int ty0 = (t / tX) * 8, tx0 = (t % tX) * 8;
  const int head = blockIdx.z;
  const int co0 = blockIdx.y << 6;
  const float* __restrict__ in = args.in[head][lvl];
  float* __restrict__ out = args.out[head][lvl];
  const float* __restrict__ wp = args.w[head];
  const int tid = threadIdx.x;
  const int cop = tid & 15, posp = tid >> 4;
  const int py = posp >> 1, px = (posp & 1) << 2;
  const int co_sub = cop << 2;
  float acc[4][4] = {};

  for (int ci0 = 0; ci0 < 256; ci0 += 8) {
    __syncthreads();
    for (int e = tid; e < 800; e += 256) {
      int ci = e / 100;
      int rem = e - ci * 100;
      int yy = rem / 10;
      int xx = rem - yy * 10;
      int gy = ty0 + yy - 1, gx = tx0 + xx - 1;
      float v = 0.f;
      if ((unsigned)gy < (unsigned)W && (unsigned)gx < (unsigned)W)
        v = in[(ci0 + ci) * HW + gy * W + gx];
      As[ci][yy][xx] = v;
    }
    const float* wb = wp + (size_t)co0 * 2304 + (size_t)ci0 * 9;
    for (int e = tid; e < 4608; e += 256) {
      int tap = e % 9;
      int ci = (e / 9) & 7;
      int co = e / 72;
      Ws[ci][tap][co] = wb[co * 2304 + ci * 9 + tap];
    }
    __syncthreads();
    #pragma unroll 2
    for (int ci = 0; ci < 8; ci++) {
      #pragma unroll
      for (int ty = 0; ty < 3; ty++) {
        const float* ar = &As[ci][py + ty][px];
        float4 av = *(const float4*)ar;
        float2 av2 = *(const float2*)(ar + 4);
        float a[6] = {av.x, av.y, av.z, av.w, av2.x, av2.y};
        #pragma unroll
        for (int tx = 0; tx < 3; tx++) {
          float4 wv = *(const float4*)&Ws[ci][ty * 3 + tx][co_sub];
          #pragma unroll
          for (int p = 0; p < 4; p++) {
            acc[p][0] = fmaf(a[tx + p], wv.x, acc[p][0]);
            acc[p][1] = fmaf(a[tx + p], wv.y, acc[p][1]);
            acc[p][2] = fmaf(a[tx + p], wv.z, acc[p][2]);
            acc[p][3] = fmaf(a[tx + p], wv.w, acc[p][3]);
          }
        }
      }
    }
  }
  const float4 bias = *(const float4*)&args.b[head][co0 + co_sub];
  const int oy = ty0 + py;
  if (oy < W) {
    #pragma unroll
    for (int p = 0; p < 4; p++) {
      int ox = tx0 + px + p;
      if (ox < W) {
        int base = oy * W + ox;
        out[(co0 + co_sub + 0) * HW + base] = fmaxf(acc[p][0] + bias.x, 0.f);
        out[(co0 + co_sub + 1) * HW + base] = fmaxf(acc[p][1] + bias.y, 0.f);
        out[(co0 + co_sub + 2) * HW + base] = fmaxf(acc[p][2] + bias.z, 0.f);
        out[(co0 + co_sub + 3) * HW + base] = fmaxf(acc[p][3] + bias.w, 0.f);
      }
    }
  }
}

// ---------------- output conv (unchanged) ----------------
template <int CO, bool SIG>
__global__ __launch_bounds__(256) void conv_out_k(OutArgs args) {
  __shared__ float As[8][10][12];
  __shared__ float Wo[8][9][CO];
  int lvl, t;
  tile_to_level(blockIdx.x, lvl, t);
  const int W = 80 >> lvl;
  const int HW = W * W;
  const int tX = (W + 7) >> 3;
  const int ty0 = (t / tX) * 8, tx0 = (t % tX) * 8;
  const float* __restrict__ in = args.in[lvl];
  const int tid = threadIdx.x;
  const int pos = tid & 63;
  const int y = pos >> 3, x = pos & 7;
  const int cset = tid >> 6;
  constexpr int NJ = (CO + 3) / 4;
  float acc[NJ] = {};

  for (int ci0 = 0; ci0 < 256; ci0 += 8) {
    __syncthreads();
    for (int e = tid; e < 800; e += 256) {
      int ci = e / 100;
      int rem = e - ci * 100;
      int yy = rem / 10;
      int xx = rem - yy * 10;
      int gy = ty0 + yy - 1, gx = tx0 + xx - 1;
      float v = 0.f;
      if ((unsigned)gy < (unsigned)W && (unsigned)gx < (unsigned)W)
        v = in[(ci0 + ci) * HW + gy * W + gx];
      As[ci][yy][xx] = v;
    }
    for (int e = tid; e < CO * 72; e += 256) {
      int tap = e % 9;
      int ci = (e / 9) & 7;
      int co = e / 72;
      Wo[ci][tap][co] = args.w[co * 2304 + (ci0 + ci) * 9 + tap];
    }
    __syncthreads();
    #pragma unroll 2
    for (int ci = 0; ci < 8; ci++) {
      #pragma unroll
      for (int ty = 0; ty < 3; ty++) {
        float a[3];
        a[0] = As[ci][y + ty][x + 0];
        a[1] = As[ci][y + ty][x + 1];
        a[2] = As[ci][y + ty][x + 2];
        #pragma unroll
        for (int tx = 0; tx < 3; tx++) {
          const float* wr = &Wo[ci][ty * 3 + tx][0];
          #pragma unroll
          for (int j = 0; j < NJ; j++) {
            int co = cset + 4 * j;
            if (co < CO) acc[j] = fmaf(a[tx], wr[co], acc[j]);
          }
        }
      }
    }
  }
  const int oy = ty0 + y, ox = tx0 + x;
  if (oy < W && ox < W) {
    const int cell = oy * W + ox;
    const int aoff = pick5(lvl, 0, 57600, 72000, 75600, 76500) * (CO / 9);
    #pragma unroll
    for (int j = 0; j < NJ; j++) {
      int co = cset + 4 * j;
      if (co < CO) {
        float v = acc[j] + args.b[co];
        if (SIG) v = 1.f / (1.f + expf(-v));
        args.dst[aoff + cell * CO + co] = v;
      }
    }
  }
}

// ---------------- init / decode ----------------
__global__ void init_k(int* meta) {
  int i = blockIdx.x * 256 + threadIdx.x;
  if (i < 1 + NBKT) meta[i] = 0;
}

__global__ __launch_bounds__(256) void decode_k(const float* __restrict__ scores,
                                                const float* __restrict__ regs,
                                                float* cand_s, float4* cand_b,
                                                int* cand_n, int* meta) {
  int n = blockIdx.x * 256 + threadIdx.x;
  if (n >= N_ANCH) return;
  int lvl = 0;
  if (n >= 57600) lvl = 1;
  if (n >= 72000) lvl = 2;
  if (n >= 75600) lvl = 3;
  if (n >= 76500) lvl = 4;
  const int aoff = pick5(lvl, 0, 57600, 72000, 75600, 76500);
  const int W = 80 >> lvl;
  int r = n - aoff;
  int a = r % 9;
  int cell = r / 9;
  int x = cell % W, y = cell / W;
  double stride = (double)(8 << lvl);
  double base = (double)(32 << lvl);
  int si = a % 3, ri = a / 3;
  double s = (si == 0) ? 1.0 : (si == 1) ? 1.2599210498948731648 : 1.5874010519681994748;
  double ratio = (ri == 0) ? 0.5 : (ri == 1) ? 1.0 : 2.0;
  double ws0 = base * s;
  double area = ws0 * ws0;
  double w = sqrt(area / ratio);
  double h = w * ratio;
  double cx = ((double)x + 0.5) * stride;
  double cy = ((double)y + 0.5) * stride;
  float ax1 = (float)(cx - 0.5 * w);
  float ay1 = (float)(cy - 0.5 * h);
  float ax2 = (float)(cx + (w - 0.5 * w));
  float ay2 = (float)(cy + (h - 0.5 * h));
  float4 rg = ((const float4*)regs)[n];
  float aw = ax2 - ax1, ah = ay2 - ay1;
  float acx = ax1 + 0.5f * aw, acy = ay1 + 0.5f * ah;
  float pcx = acx + rg.x * 0.1f * aw;
  float pcy = acy + rg.y * 0.1f * ah;
  float pw = expf(rg.z * 0.2f) * aw;
  float ph = expf(rg.w * 0.2f) * ah;
  float x1 = pcx - 0.5f * pw, y1 = pcy - 0.5f * ph;
  float x2 = pcx + 0.5f * pw, y2 = pcy + 0.5f * ph;
  x1 = fminf(fmaxf(x1, 0.f), 640.f);
  y1 = fminf(fmaxf(y1, 0.f), 640.f);
  x2 = fminf(fmaxf(x2, 0.f), 640.f);
  y2 = fminf(fmaxf(y2, 0.f), 640.f);
  float sc = scores[n];
  if (sc > 0.05f) {
    int p = atomicAdd(&meta[0], 1);
    cand_s[p] = sc;
    cand_b[p] = make_float4(x1, y1, x2, y2);
    cand_n[p] = n;
    unsigned int sb = __float_as_uint(sc);
    int bk = (int)(sb >> 16) - (int)BBASE;
    bk = max(0, min(NBKT - 1, bk));
    atomicAdd(&meta[1 + bk], 1);
  }
}

// ---------------- sort-based exact greedy NMS, one block, 512 threads ----------------
// greedy NMS == sweep in (score desc, anchor-id asc) order keeping candidates
// with IoU <= 0.5 vs all previously kept. Top score band (<=4096) selected via
// histogram, sorted with LDS bitonic sort, swept with per-lane kept-box checks.
// Band refill + 64-bit pivot bisection fallback keep it exact for any input.
__global__ __launch_bounds__(512) void nms2_k(const float* __restrict__ cs,
                                              const float4* __restrict__ cb,
                                              const int* __restrict__ cn,
                                              const int* __restrict__ meta,
                                              float* __restrict__ out) {
  __shared__ unsigned long long skey[SORT_N];  // 32 KB
  __shared__ int sidx[SORT_N];                 // 16 KB
  __shared__ int suf[NBKT];                    // 4 KB
  __shared__ float kx1[300], ky1[300], kx2[300], ky2[300], kar[300];  // ~6 KB
  __shared__ int sh_i[8];
  const int tid = threadIdx.x;
  const int m = min(meta[0], N_ANCH);

  // histogram -> inclusive suffix scan
  for (int b = tid; b < NBKT; b += 512) suf[b] = meta[1 + b];
  __syncthreads();
  for (int off = 1; off < NBKT; off <<= 1) {
    int v[2];
    for (int q = 0, b = tid; b < NBKT; b += 512, q++)
      v[q] = suf[b] + ((b + off < NBKT) ? suf[b + off] : 0);
    __syncthreads();
    for (int q = 0, b = tid; b < NBKT; b += 512, q++) suf[b] = v[q];
    __syncthreads();
  }

  int nk = 0;
  unsigned long long hi64 = ~0ULL;
  int processed = 0;

  while (nk < 300 && processed < m) {
    // base = count of keys >= hi64
    int base = 0;
    if (hi64 != ~0ULL) {
      if (tid == 0) sh_i[4] = 0;
      __syncthreads();
      int c = 0;
      for (int j = tid; j < m; j += 512) {
        unsigned long long K = ((unsigned long long)__float_as_uint(cs[j]) << 32) |
                               (unsigned int)(~cn[j]);
        if (K >= hi64) c++;
      }
      atomicAdd(&sh_i[4], c);
      __syncthreads();
      base = sh_i[4];
      __syncthreads();
    }
    // select band lower bucket T: minimal T with 1 <= suf[T]-base <= SORT_N
    if (tid == 0) sh_i[3] = NBKT + 1;
    __syncthreads();
    for (int T = tid; T < NBKT; T += 512) {
      unsigned long long lo =
          (T == 0) ? 0ULL : ((unsigned long long)(((unsigned)T + BBASE) << 16) << 32);
      int c = suf[T] - base;
      if (lo < hi64 && c >= 1 && c <= SORT_N) atomicMin(&sh_i[3], T);
    }
    __syncthreads();
    int T = sh_i[3];
    __syncthreads();
    unsigned long long lo64;
    if (T <= NBKT) {
      lo64 = (T == 0) ? 0ULL : ((unsigned long long)(((unsigned)T + BBASE) << 16) << 32);
    } else {
      // fat-bucket fallback: bisect 64-bit pivot, f(P)=count[P,hi64) decreasing
      unsigned long long L = 0, H = hi64;
      while (H - L > 1) {
        unsigned long long mid = L + ((H - L) >> 1);
        if (tid == 0) sh_i[4] = 0;
        __syncthreads();
        int c = 0;
        for (int j = tid; j < m; j += 512) {
          unsigned long long K = ((unsigned long long)__float_as_uint(cs[j]) << 32) |
                                 (unsigned int)(~cn[j]);
          if (K >= mid && K < hi64) c++;
        }
        atomicAdd(&sh_i[4], c);
        __syncthreads();
        int cc = sh_i[4];
        __syncthreads();
        if (cc > SORT_N) L = mid; else H = mid;
      }
      lo64 = H;
    }
    // gather band [lo64, hi64)
    if (tid == 0) sh_i[0] = 0;
    __syncthreads();
    for (int j = tid; j < m; j += 512) {
      unsigned long long K = ((unsigned long long)__float_as_uint(cs[j]) << 32) |
                             (unsigned int)(~cn[j]);
      if (K >= lo64 && K < hi64) {
        int p = atomicAdd(&sh_i[0], 1);
        if (p < SORT_N) { skey[p] = K; sidx[p] = j; }
      }
    }
    __syncthreads();
    int bn = min(sh_i[0], SORT_N);
    __syncthreads();
    for (int p = bn + tid; p < SORT_N; p += 512) { skey[p] = 0; sidx[p] = 0; }
    __syncthreads();
    // bitonic sort descending on skey (payload sidx)
    for (int k = 2; k <= SORT_N; k <<= 1) {
      for (int jj = k >> 1; jj > 0; jj >>= 1) {
        for (int i = tid; i < SORT_N; i += 512) {
          int l = i ^ jj;
          if (l > i) {
            unsigned long long a = skey[i], b2 = skey[l];
            bool desc = ((i & k) == 0);
            if ((a < b2) == desc) {
              skey[i] = b2; skey[l] = a;
              int t2 = sidx[i]; sidx[i] = sidx[l]; sidx[l] = t2;
            }
          }
        }
        __syncthreads();
      }
    }
    // sweep in sorted order with next-box prefetch
    float4 bc = (bn > 0) ? cb[sidx[0]] : make_float4(0.f, 0.f, 0.f, 0.f);
    int pos = 0;
    while (pos < bn && nk < 300) {
      float4 b = bc;
      unsigned long long K = skey[pos];
      if (pos + 1 < bn) bc = cb[sidx[pos + 1]];
      if (tid == 0) sh_i[1] = 0;
      __syncthreads();
      float ar = (b.z - b.x) * (b.w - b.y);
      if (tid < nk) {
        float xx1 = fmaxf(kx1[tid], b.x), yy1 = fmaxf(ky1[tid], b.y);
        float xx2 = fminf(kx2[tid], b.z), yy2 = fminf(ky2[tid], b.w);
        float inter = fmaxf(xx2 - xx1, 0.f) * fmaxf(yy2 - yy1, 0.f);
        float iou = inter / (ar + kar[tid] - inter + 1e-8f);
        if (iou > 0.5f) sh_i[1] = 1;
      }
      __syncthreads();
      int flag = sh_i[1];
      if (!flag) {
        if (tid == 0) {
          kx1[nk] = b.x; ky1[nk] = b.y; kx2[nk] = b.z; ky2[nk] = b.w; kar[nk] = ar;
          out[nk] = __uint_as_float((unsigned int)(K >> 32));
          out[300 + nk] = 0.0f;
          out[600 + 4 * nk + 0] = b.x;
          out[600 + 4 * nk + 1] = b.y;
          out[600 + 4 * nk + 2] = b.z;
          out[600 + 4 * nk + 3] = b.w;
        }
        nk++;
      }
      pos++;
      __syncthreads();
    }
    processed = base + bn;
    hi64 = lo64;
  }
  // fill remaining output slots
  __syncthreads();
  for (int r = nk + tid; r < 300; r += 512) {
    out[r] = 0.f;
    out[300 + r] = -1.f;
    out[600 + 4 * r + 0] = 0.f;
    out[600 + 4 * r + 1] = 0.f;
    out[600 + 4 * r + 2] = 0.f;
    out[600 + 4 * r + 3] = 0.f;
  }
}

// ---------------- host ----------------
extern "C" void kernel_launch(void* const* d_in, const int* in_sizes, int n_in,
                              void* d_out, int out_size, void* d_ws, size_t ws_size,
                              hipStream_t stream) {
  (void)in_sizes; (void)n_in; (void)out_size; (void)ws_size;
  const float* feats[5];
  for (int l = 0; l < 5; l++) feats[l] = (const float*)d_in[1 + l];
  const float* cls_w = (const float*)d_in[6];
  const float* cls_b = (const float*)d_in[7];
  const float* cls_ow = (const float*)d_in[8];
  const float* cls_ob = (const float*)d_in[9];
  const float* reg_w = (const float*)d_in[10];
  const float* reg_b = (const float*)d_in[11];
  const float* reg_ow = (const float*)d_in[12];
  const float* reg_ob = (const float*)d_in[13];

  static const int AOFF[5] = {0, 1638400, 2048000, 2150400, 2176000}; // 256*cumHW
  const size_t ACT = 2182400;  // 256*8525 floats per head

  float* ws = (float*)d_ws;
  float* bufA = ws;                       // 2*ACT
  float* bufB = bufA + 2 * ACT;           // 2*ACT
  float* scores = bufB + 2 * ACT;         // 76736 (padded)
  float* regs = scores + 76736;           // 306912 (padded)
  float* cand_s = regs + 306912;          // 76736
  float* cand_b = cand_s + 76736;         // 306944
  int* cand_n = (int*)(cand_b + 306944);  // 76736 ints
  int* meta = cand_n + 76736;             // [0]=cnt, [1..NBKT]=hist

  float* bufs[2] = {bufA, bufB};
  TrunkArgs ta;
  for (int layer = 0; layer < 4; layer++) {
    for (int h = 0; h < 2; h++) {
      ta.w[h] = (h ? reg_w : cls_w) + (size_t)layer * 589824;
      ta.b[h] = (h ? reg_b : cls_b) + layer * 256;
      for (int l = 0; l < 5; l++) {
        ta.out[h][l] = bufs[layer & 1] + h * ACT + AOFF[l];
        ta.in[h][l] = (layer == 0) ? feats[l] : (const float*)(bufs[(layer - 1) & 1] + h * ACT + AOFF[l]);
      }
    }
    conv_trunk<<<dim3(139, 4, 2), dim3(256), 0, stream>>>(ta);
  }

  OutArgs oc, og;
  for (int l = 0; l < 5; l++) {
    oc.in[l] = bufB + 0 * ACT + AOFF[l];
    og.in[l] = bufB + 1 * ACT + AOFF[l];
  }
  oc.w = cls_ow; oc.b = cls_ob; oc.dst = scores;
  og.w = reg_ow; og.b = reg_ob; og.dst = regs;
  conv_out_k<9, true><<<dim3(139), dim3(256), 0, stream>>>(oc);
  conv_out_k<36, false><<<dim3(139), dim3(256), 0, stream>>>(og);

  init_k<<<dim3(5), dim3(256), 0, stream>>>(meta);
  decode_k<<<dim3((N_ANCH + 255) / 256), dim3(256), 0, stream>>>(scores, regs, cand_s,
                                                                 (float4*)cand_b, cand_n, meta);
  nms2_k<<<dim3(1), dim3(512), 0, stream>>>(cand_s, (const float4*)cand_b, cand_n, meta,
                                            (float*)d_out);
}

// Round 4
// 2126.636 us; speedup vs baseline: 2.4501x; 1.3153x over previous
//
#include <hip/hip_runtime.h>
#include <math.h>

#define N_ANCH 76725
#define SORT_N 4096
#define NBKT 1024
#define BBASE 0x3D40u

struct TrunkArgs {
  const float* in[2][5];
  float* out[2][5];
  const float* w[2];
  const float* b[2];
};

struct Out2Args {
  const float* in[2][5];  // [head][lvl]
  const float* w[2];      // cls_ow, reg_ow
  const float* b[2];      // cls_ob, reg_ob
  float* dst[2];          // scores (per-anchor), regs (per-anchor x4)
};

__device__ __forceinline__ int pick5(int l, int a, int b, int c, int d, int e) {
  int r = a;
  if (l == 1) r = b;
  if (l == 2) r = c;
  if (l == 3) r = d;
  if (l == 4) r = e;
  return r;
}

__device__ __forceinline__ void tile_to_level(int tile, int& lvl, int& t) {
  int l = 0;
  if (tile >= 100) l = 1;
  if (tile >= 125) l = 2;
  if (tile >= 134) l = 3;
  if (tile >= 138) l = 4;
  lvl = l;
  t = tile - pick5(l, 0, 100, 125, 134, 138);
}

// ---------------- trunk conv: 256->256, 3x3, SAME, ReLU (unchanged) ----------------
__global__ __launch_bounds__(256) void conv_trunk(TrunkArgs args) {
  __shared__ float As[8][10][12];
  __shared__ float Ws[8][9][68];
  int lvl, t;
  tile_to_level(blockIdx.x, lvl, t);
  const int W = 80 >> lvl;
  const int HW = W * W;
  const int tX = (W + 7) >> 3;
  const int ty0 = (t / tX) * 8, tx0 = (t % tX) * 8;
  const int head = blockIdx.z;
  const int co0 = blockIdx.y << 6;
  const float* __restrict__ in = args.in[head][lvl];
  float* __restrict__ out = args.out[head][lvl];
  const float* __restrict__ wp = args.w[head];
  const int tid = threadIdx.x;
  const int cop = tid & 15, posp = tid >> 4;
  const int py = posp >> 1, px = (posp & 1) << 2;
  const int co_sub = cop << 2;
  float acc[4][4] = {};

  for (int ci0 = 0; ci0 < 256; ci0 += 8) {
    __syncthreads();
    for (int e = tid; e < 800; e += 256) {
      int ci = e / 100;
      int rem = e - ci * 100;
      int yy = rem / 10;
      int xx = rem - yy * 10;
      int gy = ty0 + yy - 1, gx = tx0 + xx - 1;
      float v = 0.f;
      if ((unsigned)gy < (unsigned)W && (unsigned)gx < (unsigned)W)
        v = in[(ci0 + ci) * HW + gy * W + gx];
      As[ci][yy][xx] = v;
    }
    const float* wb = wp + (size_t)co0 * 2304 + (size_t)ci0 * 9;
    for (int e = tid; e < 4608; e += 256) {
      int tap = e % 9;
      int ci = (e / 9) & 7;
      int co = e / 72;
      Ws[ci][tap][co] = wb[co * 2304 + ci * 9 + tap];
    }
    __syncthreads();
    #pragma unroll 2
    for (int ci = 0; ci < 8; ci++) {
      #pragma unroll
      for (int ty = 0; ty < 3; ty++) {
        const float* ar = &As[ci][py + ty][px];
        float4 av = *(const float4*)ar;
        float2 av2 = *(const float2*)(ar + 4);
        float a[6] = {av.x, av.y, av.z, av.w, av2.x, av2.y};
        #pragma unroll
        for (int tx = 0; tx < 3; tx++) {
          float4 wv = *(const float4*)&Ws[ci][ty * 3 + tx][co_sub];
          #pragma unroll
          for (int p = 0; p < 4; p++) {
            acc[p][0] = fmaf(a[tx + p], wv.x, acc[p][0]);
            acc[p][1] = fmaf(a[tx + p], wv.y, acc[p][1]);
            acc[p][2] = fmaf(a[tx + p], wv.z, acc[p][2]);
            acc[p][3] = fmaf(a[tx + p], wv.w, acc[p][3]);
          }
        }
      }
    }
  }
  const float4 bias = *(const float4*)&args.b[head][co0 + co_sub];
  const int oy = ty0 + py;
  if (oy < W) {
    #pragma unroll
    for (int p = 0; p < 4; p++) {
      int ox = tx0 + px + p;
      if (ox < W) {
        int base = oy * W + ox;
        out[(co0 + co_sub + 0) * HW + base] = fmaxf(acc[p][0] + bias.x, 0.f);
        out[(co0 + co_sub + 1) * HW + base] = fmaxf(acc[p][1] + bias.y, 0.f);
        out[(co0 + co_sub + 2) * HW + base] = fmaxf(acc[p][2] + bias.z, 0.f);
        out[(co0 + co_sub + 3) * HW + base] = fmaxf(acc[p][3] + bias.w, 0.f);
      }
    }
  }
}

// ---------------- fused output convs: grid (139 tiles, 5 co-groups) ----------------
// group 0 = cls head (co 0..8, sigmoid); groups 1..4 = reg head co-chunks of 9.
// lane = position (8x8), wave = co-trio -> weight LDS reads are wave-uniform
// broadcasts (conflict-free). FMA order per output identical to the original
// (ci asc, ty asc, tx asc) -> bit-exact.
__global__ __launch_bounds__(192) void conv_out2(Out2Args args) {
  __shared__ float As[8][10][12];
  __shared__ float Wg[8][9][12];   // 9 co used, pad to 12
  int lvl, t;
  tile_to_level(blockIdx.x, lvl, t);
  const int g = blockIdx.y;
  const int head = (g == 0) ? 0 : 1;
  const int co0 = (g == 0) ? 0 : (g - 1) * 9;
  const int W = 80 >> lvl;
  const int HW = W * W;
  const int tX = (W + 7) >> 3;
  const int ty0 = (t / tX) * 8, tx0 = (t % tX) * 8;
  const float* __restrict__ in = args.in[head][lvl];
  const float* __restrict__ wp = args.w[head] + (size_t)co0 * 2304;
  const int tid = threadIdx.x;
  const int lane = tid & 63;
  const int wv = tid >> 6;       // 0..2 -> co trio {3wv, 3wv+1, 3wv+2}
  const int y = lane >> 3, x = lane & 7;
  float acc0 = 0.f, acc1 = 0.f, acc2 = 0.f;

  for (int ci0 = 0; ci0 < 256; ci0 += 8) {
    __syncthreads();
    for (int e = tid; e < 800; e += 192) {
      int ci = e / 100;
      int rem = e - ci * 100;
      int yy = rem / 10;
      int xx = rem - yy * 10;
      int gy = ty0 + yy - 1, gx = tx0 + xx - 1;
      float v = 0.f;
      if ((unsigned)gy < (unsigned)W && (unsigned)gx < (unsigned)W)
        v = in[(ci0 + ci) * HW + gy * W + gx];
      As[ci][yy][xx] = v;
    }
    for (int e = tid; e < 648; e += 192) {
      int co = e / 72;
      int r = e - co * 72;          // r = ci*9 + tap, contiguous in global
      int ci = r / 9;
      int tap = r - ci * 9;
      Wg[ci][tap][co] = wp[(size_t)co * 2304 + (size_t)ci0 * 9 + r];
    }
    __syncthreads();
    #pragma unroll 2
    for (int ci = 0; ci < 8; ci++) {
      #pragma unroll
      for (int ty = 0; ty < 3; ty++) {
        float a0 = As[ci][y + ty][x + 0];
        float a1 = As[ci][y + ty][x + 1];
        float a2 = As[ci][y + ty][x + 2];
        #pragma unroll
        for (int tx = 0; tx < 3; tx++) {
          float av = (tx == 0) ? a0 : (tx == 1) ? a1 : a2;
          const float* wr = &Wg[ci][ty * 3 + tx][3 * wv];
          acc0 = fmaf(av, wr[0], acc0);
          acc1 = fmaf(av, wr[1], acc1);
          acc2 = fmaf(av, wr[2], acc2);
        }
      }
    }
  }
  const int oy = ty0 + y, ox = tx0 + x;
  if (oy < W && ox < W) {
    const int cell = oy * W + ox;
    const int aoff = pick5(lvl, 0, 57600, 72000, 75600, 76500);
    float* dst = args.dst[head];
    const float* bias = args.b[head];
    #pragma unroll
    for (int c = 0; c < 3; c++) {
      int co = co0 + 3 * wv + c;
      float v = ((c == 0) ? acc0 : (c == 1) ? acc1 : acc2) + bias[co];
      if (head == 0) {
        v = 1.f / (1.f + expf(-v));
        dst[aoff + cell * 9 + co] = v;
      } else {
        dst[(size_t)aoff * 4 + cell * 36 + co] = v;
      }
    }
  }
}

// ---------------- init / decode ----------------
__global__ void init_k(int* meta) {
  int i = blockIdx.x * 256 + threadIdx.x;
  if (i < 1 + NBKT) meta[i] = 0;
}

__global__ __launch_bounds__(256) void decode_k(const float* __restrict__ scores,
                                                const float* __restrict__ regs,
                                                float* cand_s, float4* cand_b,
                                                int* cand_n, int* meta) {
  int n = blockIdx.x * 256 + threadIdx.x;
  if (n >= N_ANCH) return;
  int lvl = 0;
  if (n >= 57600) lvl = 1;
  if (n >= 72000) lvl = 2;
  if (n >= 75600) lvl = 3;
  if (n >= 76500) lvl = 4;
  const int aoff = pick5(lvl, 0, 57600, 72000, 75600, 76500);
  const int W = 80 >> lvl;
  int r = n - aoff;
  int a = r % 9;
  int cell = r / 9;
  int x = cell % W, y = cell / W;
  double stride = (double)(8 << lvl);
  double base = (double)(32 << lvl);
  int si = a % 3, ri = a / 3;
  double s = (si == 0) ? 1.0 : (si == 1) ? 1.2599210498948731648 : 1.5874010519681994748;
  double ratio = (ri == 0) ? 0.5 : (ri == 1) ? 1.0 : 2.0;
  double ws0 = base * s;
  double area = ws0 * ws0;
  double w = sqrt(area / ratio);
  double h = w * ratio;
  double cx = ((double)x + 0.5) * stride;
  double cy = ((double)y + 0.5) * stride;
  float ax1 = (float)(cx - 0.5 * w);
  float ay1 = (float)(cy - 0.5 * h);
  float ax2 = (float)(cx + (w - 0.5 * w));
  float ay2 = (float)(cy + (h - 0.5 * h));
  float4 rg = ((const float4*)regs)[n];
  float aw = ax2 - ax1, ah = ay2 - ay1;
  float acx = ax1 + 0.5f * aw, acy = ay1 + 0.5f * ah;
  float pcx = acx + rg.x * 0.1f * aw;
  float pcy = acy + rg.y * 0.1f * ah;
  float pw = expf(rg.z * 0.2f) * aw;
  float ph = expf(rg.w * 0.2f) * ah;
  float x1 = pcx - 0.5f * pw, y1 = pcy - 0.5f * ph;
  float x2 = pcx + 0.5f * pw, y2 = pcy + 0.5f * ph;
  x1 = fminf(fmaxf(x1, 0.f), 640.f);
  y1 = fminf(fmaxf(y1, 0.f), 640.f);
  x2 = fminf(fmaxf(x2, 0.f), 640.f);
  y2 = fminf(fmaxf(y2, 0.f), 640.f);
  float sc = scores[n];
  if (sc > 0.05f) {
    int p = atomicAdd(&meta[0], 1);
    cand_s[p] = sc;
    cand_b[p] = make_float4(x1, y1, x2, y2);
    cand_n[p] = n;
    unsigned int sb = __float_as_uint(sc);
    int bk = (int)(sb >> 16) - (int)BBASE;
    bk = max(0, min(NBKT - 1, bk));
    atomicAdd(&meta[1 + bk], 1);
  }
}

// ---------------- sort-based exact greedy NMS (unchanged) ----------------
__global__ __launch_bounds__(512) void nms2_k(const float* __restrict__ cs,
                                              const float4* __restrict__ cb,
                                              const int* __restrict__ cn,
                                              const int* __restrict__ meta,
                                              float* __restrict__ out) {
  __shared__ unsigned long long skey[SORT_N];
  __shared__ int sidx[SORT_N];
  __shared__ int suf[NBKT];
  __shared__ float kx1[300], ky1[300], kx2[300], ky2[300], kar[300];
  __shared__ int sh_i[8];
  const int tid = threadIdx.x;
  const int m = min(meta[0], N_ANCH);

  for (int b = tid; b < NBKT; b += 512) suf[b] = meta[1 + b];
  __syncthreads();
  for (int off = 1; off < NBKT; off <<= 1) {
    int v[2];
    for (int q = 0, b = tid; b < NBKT; b += 512, q++)
      v[q] = suf[b] + ((b + off < NBKT) ? suf[b + off] : 0);
    __syncthreads();
    for (int q = 0, b = tid; b < NBKT; b += 512, q++) suf[b] = v[q];
    __syncthreads();
  }

  int nk = 0;
  unsigned long long hi64 = ~0ULL;
  int processed = 0;

  while (nk < 300 && processed < m) {
    int base = 0;
    if (hi64 != ~0ULL) {
      if (tid == 0) sh_i[4] = 0;
      __syncthreads();
      int c = 0;
      for (int j = tid; j < m; j += 512) {
        unsigned long long K = ((unsigned long long)__float_as_uint(cs[j]) << 32) |
                               (unsigned int)(~cn[j]);
        if (K >= hi64) c++;
      }
      atomicAdd(&sh_i[4], c);
      __syncthreads();
      base = sh_i[4];
      __syncthreads();
    }
    if (tid == 0) sh_i[3] = NBKT + 1;
    __syncthreads();
    for (int T = tid; T < NBKT; T += 512) {
      unsigned long long lo =
          (T == 0) ? 0ULL : ((unsigned long long)(((unsigned)T + BBASE) << 16) << 32);
      int c = suf[T] - base;
      if (lo < hi64 && c >= 1 && c <= SORT_N) atomicMin(&sh_i[3], T);
    }
    __syncthreads();
    int T = sh_i[3];
    __syncthreads();
    unsigned long long lo64;
    if (T <= NBKT) {
      lo64 = (T == 0) ? 0ULL : ((unsigned long long)(((unsigned)T + BBASE) << 16) << 32);
    } else {
      unsigned long long L = 0, H = hi64;
      while (H - L > 1) {
        unsigned long long mid = L + ((H - L) >> 1);
        if (tid == 0) sh_i[4] = 0;
        __syncthreads();
        int c = 0;
        for (int j = tid; j < m; j += 512) {
          unsigned long long K = ((unsigned long long)__float_as_uint(cs[j]) << 32) |
                                 (unsigned int)(~cn[j]);
          if (K >= mid && K < hi64) c++;
        }
        atomicAdd(&sh_i[4], c);
        __syncthreads();
        int cc = sh_i[4];
        __syncthreads();
        if (cc > SORT_N) L = mid; else H = mid;
      }
      lo64 = H;
    }
    if (tid == 0) sh_i[0] = 0;
    __syncthreads();
    for (int j = tid; j < m; j += 512) {
      unsigned long long K = ((unsigned long long)__float_as_uint(cs[j]) << 32) |
                             (unsigned int)(~cn[j]);
      if (K >= lo64 && K < hi64) {
        int p = atomicAdd(&sh_i[0], 1);
        if (p < SORT_N) { skey[p] = K; sidx[p] = j; }
      }
    }
    __syncthreads();
    int bn = min(sh_i[0], SORT_N);
    __syncthreads();
    for (int p = bn + tid; p < SORT_N; p += 512) { skey[p] = 0; sidx[p] = 0; }
    __syncthreads();
    for (int k = 2; k <= SORT_N; k <<= 1) {
      for (int jj = k >> 1; jj > 0; jj >>= 1) {
        for (int i = tid; i < SORT_N; i += 512) {
          int l = i ^ jj;
          if (l > i) {
            unsigned long long a = skey[i], b2 = skey[l];
            bool desc = ((i & k) == 0);
            if ((a < b2) == desc) {
              skey[i] = b2; skey[l] = a;
              int t2 = sidx[i]; sidx[i] = sidx[l]; sidx[l] = t2;
            }
          }
        }
        __syncthreads();
      }
    }
    float4 bc = (bn > 0) ? cb[sidx[0]] : make_float4(0.f, 0.f, 0.f, 0.f);
    int pos = 0;
    while (pos < bn && nk < 300) {
      float4 b = bc;
      unsigned long long K = skey[pos];
      if (pos + 1 < bn) bc = cb[sidx[pos + 1]];
      if (tid == 0) sh_i[1] = 0;
      __syncthreads();
      float ar = (b.z - b.x) * (b.w - b.y);
      if (tid < nk) {
        float xx1 = fmaxf(kx1[tid], b.x), yy1 = fmaxf(ky1[tid], b.y);
        float xx2 = fminf(kx2[tid], b.z), yy2 = fminf(ky2[tid], b.w);
        float inter = fmaxf(xx2 - xx1, 0.f) * fmaxf(yy2 - yy1, 0.f);
        float iou = inter / (ar + kar[tid] - inter + 1e-8f);
        if (iou > 0.5f) sh_i[1] = 1;
      }
      __syncthreads();
      int flag = sh_i[1];
      if (!flag) {
        if (tid == 0) {
          kx1[nk] = b.x; ky1[nk] = b.y; kx2[nk] = b.z; ky2[nk] = b.w; kar[nk] = ar;
          out[nk] = __uint_as_float((unsigned int)(K >> 32));
          out[300 + nk] = 0.0f;
          out[600 + 4 * nk + 0] = b.x;
          out[600 + 4 * nk + 1] = b.y;
          out[600 + 4 * nk + 2] = b.z;
          out[600 + 4 * nk + 3] = b.w;
        }
        nk++;
      }
      pos++;
      __syncthreads();
    }
    processed = base + bn;
    hi64 = lo64;
  }
  __syncthreads();
  for (int r = nk + tid; r < 300; r += 512) {
    out[r] = 0.f;
    out[300 + r] = -1.f;
    out[600 + 4 * r + 0] = 0.f;
    out[600 + 4 * r + 1] = 0.f;
    out[600 + 4 * r + 2] = 0.f;
    out[600 + 4 * r + 3] = 0.f;
  }
}

// ---------------- host ----------------
extern "C" void kernel_launch(void* const* d_in, const int* in_sizes, int n_in,
                              void* d_out, int out_size, void* d_ws, size_t ws_size,
                              hipStream_t stream) {
  (void)in_sizes; (void)n_in; (void)out_size; (void)ws_size;
  const float* feats[5];
  for (int l = 0; l < 5; l++) feats[l] = (const float*)d_in[1 + l];
  const float* cls_w = (const float*)d_in[6];
  const float* cls_b = (const float*)d_in[7];
  const float* cls_ow = (const float*)d_in[8];
  const float* cls_ob = (const float*)d_in[9];
  const float* reg_w = (const float*)d_in[10];
  const float* reg_b = (const float*)d_in[11];
  const float* reg_ow = (const float*)d_in[12];
  const float* reg_ob = (const float*)d_in[13];

  static const int AOFF[5] = {0, 1638400, 2048000, 2150400, 2176000}; // 256*cumHW
  const size_t ACT = 2182400;  // 256*8525 floats per head

  float* ws = (float*)d_ws;
  float* bufA = ws;                       // 2*ACT
  float* bufB = bufA + 2 * ACT;           // 2*ACT
  float* scores = bufB + 2 * ACT;         // 76736 (padded)
  float* regs = scores + 76736;           // 306912 (padded)
  float* cand_s = regs + 306912;          // 76736
  float* cand_b = cand_s + 76736;         // 306944
  int* cand_n = (int*)(cand_b + 306944);  // 76736 ints
  int* meta = cand_n + 76736;             // [0]=cnt, [1..NBKT]=hist

  float* bufs[2] = {bufA, bufB};
  TrunkArgs ta;
  for (int layer = 0; layer < 4; layer++) {
    for (int h = 0; h < 2; h++) {
      ta.w[h] = (h ? reg_w : cls_w) + (size_t)layer * 589824;
      ta.b[h] = (h ? reg_b : cls_b) + layer * 256;
      for (int l = 0; l < 5; l++) {
        ta.out[h][l] = bufs[layer & 1] + h * ACT + AOFF[l];
        ta.in[h][l] = (layer == 0) ? feats[l] : (const float*)(bufs[(layer - 1) & 1] + h * ACT + AOFF[l]);
      }
    }
    conv_trunk<<<dim3(139, 4, 2), dim3(256), 0, stream>>>(ta);
  }

  Out2Args oa;
  for (int l = 0; l < 5; l++) {
    oa.in[0][l] = bufB + 0 * ACT + AOFF[l];
    oa.in[1][l] = bufB + 1 * ACT + AOFF[l];
  }
  oa.w[0] = cls_ow; oa.w[1] = reg_ow;
  oa.b[0] = cls_ob; oa.b[1] = reg_ob;
  oa.dst[0] = scores; oa.dst[1] = regs;
  conv_out2<<<dim3(139, 5), dim3(192), 0, stream>>>(oa);

  init_k<<<dim3(5), dim3(256), 0, stream>>>(meta);
  decode_k<<<dim3((N_ANCH + 255) / 256), dim3(256), 0, stream>>>(scores, regs, cand_s,
                                                                 (float4*)cand_b, cand_n, meta);
  nms2_k<<<dim3(1), dim3(512), 0, stream>>>(cand_s, (const float4*)cand_b, cand_n, meta,
                                            (float*)d_out);
}

// Round 5
// 1979.267 us; speedup vs baseline: 2.6325x; 1.0745x over previous
//
#include <hip/hip_runtime.h>
#include <math.h>

#define N_ANCH 76725
#define SORT_N 4096
#define NBKT 1024
#define BBASE 0x3D40u

struct TrunkArgs {
  const float* in[2][5];
  float* out[2][5];
  const float* w[2];
  const float* b[2];
};

struct Out2Args {
  const float* in[2][5];  // [head][lvl]
  const float* w[2];      // cls_ow, reg_ow
  const float* b[2];      // cls_ob, reg_ob
  float* dst[2];          // scores (per-anchor), regs (per-anchor x4)
};

__device__ __forceinline__ int pick5(int l, int a, int b, int c, int d, int e) {
  int r = a;
  if (l == 1) r = b;
  if (l == 2) r = c;
  if (l == 3) r = d;
  if (l == 4) r = e;
  return r;
}

__device__ __forceinline__ void tile_to_level(int tile, int& lvl, int& t) {
  int l = 0;
  if (tile >= 100) l = 1;
  if (tile >= 125) l = 2;
  if (tile >= 134) l = 3;
  if (tile >= 138) l = 4;
  lvl = l;
  t = tile - pick5(l, 0, 100, 125, 134, 138);
}

// ---------------- trunk conv: 256->256, 3x3, SAME, ReLU ----------------
// block tile: 64 positions (8x8) x 64 co, BK=8, thread tile 4 pos x 4 co.
// Software-pipelined: global loads for chunk k+1 issue before chunk k's FMA
// block (vmcnt wait lands at the reg->LDS write after compute -> latency
// hidden). Staged values & FMA order identical to R4 -> bit-exact.
__device__ __forceinline__ void ct_load(const float* __restrict__ in,
                                        const float* __restrict__ wp, int ci0,
                                        int ty0, int tx0, int W, int HW, int tid,
                                        float a_reg[4], float4 w_reg[5]) {
  const float* inc = in + ci0 * HW;
  const float* wc = wp + ci0 * 9;
  #pragma unroll
  for (int i = 0; i < 4; i++) {
    int e = tid + 256 * i;
    float v = 0.f;
    if (e < 800) {
      int ci = e / 100;
      int rem = e - ci * 100;
      int yy = rem / 10;
      int xx = rem - yy * 10;
      int gy = ty0 + yy - 1, gx = tx0 + xx - 1;
      if ((unsigned)gy < (unsigned)W && (unsigned)gx < (unsigned)W)
        v = inc[ci * HW + gy * W + gx];
    }
    a_reg[i] = v;
  }
  #pragma unroll
  for (int i = 0; i < 5; i++) {
    int e = tid + 256 * i;
    if (e < 1152) {
      int co = e / 18;
      int q = e - co * 18;
      w_reg[i] = *(const float4*)(wc + co * 2304 + 4 * q);
    }
  }
}

__device__ __forceinline__ void ct_store(int tid, const float a_reg[4],
                                         const float4 w_reg[5],
                                         float As[8][10][12], float Ws[8][9][68]) {
  #pragma unroll
  for (int i = 0; i < 4; i++) {
    int e = tid + 256 * i;
    if (e < 800) {
      int ci = e / 100;
      int rem = e - ci * 100;
      int yy = rem / 10;
      int xx = rem - yy * 10;
      As[ci][yy][xx] = a_reg[i];
    }
  }
  float* dst0 = &Ws[0][0][0];
  #pragma unroll
  for (int i = 0; i < 5; i++) {
    int e = tid + 256 * i;
    if (e < 1152) {
      int co = e / 18;
      int q = e - co * 18;
      int r = 4 * q;
      dst0[(r + 0) * 68 + co] = w_reg[i].x;
      dst0[(r + 1) * 68 + co] = w_reg[i].y;
      dst0[(r + 2) * 68 + co] = w_reg[i].z;
      dst0[(r + 3) * 68 + co] = w_reg[i].w;
    }
  }
}

__global__ __launch_bounds__(256) void conv_trunk(TrunkArgs args) {
  __shared__ float As[8][10][12];
  __shared__ float Ws[8][9][68];
  int lvl, t;
  tile_to_level(blockIdx.x, lvl, t);
  const int W = 80 >> lvl;
  const int HW = W * W;
  const int tX = (W + 7) >> 3;
  const int ty0 = (t / tX) * 8, tx0 = (t % tX) * 8;
  const int head = blockIdx.z;
  const int co0 = blockIdx.y << 6;
  const float* __restrict__ in = args.in[head][lvl];
  float* __restrict__ out = args.out[head][lvl];
  const float* __restrict__ wp = args.w[head] + (size_t)co0 * 2304;
  const int tid = threadIdx.x;
  const int cop = tid & 15, posp = tid >> 4;
  const int py = posp >> 1, px = (posp & 1) << 2;
  const int co_sub = cop << 2;
  float acc[4][4] = {};
  float a_reg[4];
  float4 w_reg[5];

  ct_load(in, wp, 0, ty0, tx0, W, HW, tid, a_reg, w_reg);
  ct_store(tid, a_reg, w_reg, As, Ws);
  __syncthreads();

  for (int ci0 = 0; ci0 < 256; ci0 += 8) {
    const bool more = (ci0 + 8) < 256;
    if (more) ct_load(in, wp, ci0 + 8, ty0, tx0, W, HW, tid, a_reg, w_reg);
    #pragma unroll 2
    for (int ci = 0; ci < 8; ci++) {
      #pragma unroll
      for (int ty = 0; ty < 3; ty++) {
        const float* ar = &As[ci][py + ty][px];
        float4 av = *(const float4*)ar;
        float2 av2 = *(const float2*)(ar + 4);
        float a[6] = {av.x, av.y, av.z, av.w, av2.x, av2.y};
        #pragma unroll
        for (int tx = 0; tx < 3; tx++) {
          float4 wv = *(const float4*)&Ws[ci][ty * 3 + tx][co_sub];
          #pragma unroll
          for (int p = 0; p < 4; p++) {
            acc[p][0] = fmaf(a[tx + p], wv.x, acc[p][0]);
            acc[p][1] = fmaf(a[tx + p], wv.y, acc[p][1]);
            acc[p][2] = fmaf(a[tx + p], wv.z, acc[p][2]);
            acc[p][3] = fmaf(a[tx + p], wv.w, acc[p][3]);
          }
        }
      }
    }
    if (more) {
      __syncthreads();
      ct_store(tid, a_reg, w_reg, As, Ws);
      __syncthreads();
    }
  }
  const float4 bias = *(const float4*)&args.b[head][co0 + co_sub];
  const int oy = ty0 + py;
  if (oy < W) {
    #pragma unroll
    for (int p = 0; p < 4; p++) {
      int ox = tx0 + px + p;
      if (ox < W) {
        int base = oy * W + ox;
        out[(co0 + co_sub + 0) * HW + base] = fmaxf(acc[p][0] + bias.x, 0.f);
        out[(co0 + co_sub + 1) * HW + base] = fmaxf(acc[p][1] + bias.y, 0.f);
        out[(co0 + co_sub + 2) * HW + base] = fmaxf(acc[p][2] + bias.z, 0.f);
        out[(co0 + co_sub + 3) * HW + base] = fmaxf(acc[p][3] + bias.w, 0.f);
      }
    }
  }
}

// ---------------- fused output convs (unchanged from R4) ----------------
__global__ __launch_bounds__(192) void conv_out2(Out2Args args) {
  __shared__ float As[8][10][12];
  __shared__ float Wg[8][9][12];
  int lvl, t;
  tile_to_level(blockIdx.x, lvl, t);
  const int g = blockIdx.y;
  const int head = (g == 0) ? 0 : 1;
  const int co0 = (g == 0) ? 0 : (g - 1) * 9;
  const int W = 80 >> lvl;
  const int HW = W * W;
  const int tX = (W + 7) >> 3;
  const int ty0 = (t / tX) * 8, tx0 = (t % tX) * 8;
  const float* __restrict__ in = args.in[head][lvl];
  const float* __restrict__ wp = args.w[head] + (size_t)co0 * 2304;
  const int tid = threadIdx.x;
  const int lane = tid & 63;
  const int wv = tid >> 6;
  const int y = lane >> 3, x = lane & 7;
  float acc0 = 0.f, acc1 = 0.f, acc2 = 0.f;

  for (int ci0 = 0; ci0 < 256; ci0 += 8) {
    __syncthreads();
    for (int e = tid; e < 800; e += 192) {
      int ci = e / 100;
      int rem = e - ci * 100;
      int yy = rem / 10;
      int xx = rem - yy * 10;
      int gy = ty0 + yy - 1, gx = tx0 + xx - 1;
      float v = 0.f;
      if ((unsigned)gy < (unsigned)W && (unsigned)gx < (unsigned)W)
        v = in[(ci0 + ci) * HW + gy * W + gx];
      As[ci][yy][xx] = v;
    }
    for (int e = tid; e < 648; e += 192) {
      int co = e / 72;
      int r = e - co * 72;
      int ci = r / 9;
      int tap = r - ci * 9;
      Wg[ci][tap][co] = wp[(size_t)co * 2304 + (size_t)ci0 * 9 + r];
    }
    __syncthreads();
    #pragma unroll 2
    for (int ci = 0; ci < 8; ci++) {
      #pragma unroll
      for (int ty = 0; ty < 3; ty++) {
        float a0 = As[ci][y + ty][x + 0];
        float a1 = As[ci][y + ty][x + 1];
        float a2 = As[ci][y + ty][x + 2];
        #pragma unroll
        for (int tx = 0; tx < 3; tx++) {
          float av = (tx == 0) ? a0 : (tx == 1) ? a1 : a2;
          const float* wr = &Wg[ci][ty * 3 + tx][3 * wv];
          acc0 = fmaf(av, wr[0], acc0);
          acc1 = fmaf(av, wr[1], acc1);
          acc2 = fmaf(av, wr[2], acc2);
        }
      }
    }
  }
  const int oy = ty0 + y, ox = tx0 + x;
  if (oy < W && ox < W) {
    const int cell = oy * W + ox;
    const int aoff = pick5(lvl, 0, 57600, 72000, 75600, 76500);
    float* dst = args.dst[head];
    const float* bias = args.b[head];
    #pragma unroll
    for (int c = 0; c < 3; c++) {
      int co = co0 + 3 * wv + c;
      float v = ((c == 0) ? acc0 : (c == 1) ? acc1 : acc2) + bias[co];
      if (head == 0) {
        v = 1.f / (1.f + expf(-v));
        dst[aoff + cell * 9 + co] = v;
      } else {
        dst[(size_t)aoff * 4 + cell * 36 + co] = v;
      }
    }
  }
}

// ---------------- init / decode (unchanged) ----------------
__global__ void init_k(int* meta) {
  int i = blockIdx.x * 256 + threadIdx.x;
  if (i < 1 + NBKT) meta[i] = 0;
}

__global__ __launch_bounds__(256) void decode_k(const float* __restrict__ scores,
                                                const float* __restrict__ regs,
                                                float* cand_s, float4* cand_b,
                                                int* cand_n, int* meta) {
  int n = blockIdx.x * 256 + threadIdx.x;
  if (n >= N_ANCH) return;
  int lvl = 0;
  if (n >= 57600) lvl = 1;
  if (n >= 72000) lvl = 2;
  if (n >= 75600) lvl = 3;
  if (n >= 76500) lvl = 4;
  const int aoff = pick5(lvl, 0, 57600, 72000, 75600, 76500);
  const int W = 80 >> lvl;
  int r = n - aoff;
  int a = r % 9;
  int cell = r / 9;
  int x = cell % W, y = cell / W;
  double stride = (double)(8 << lvl);
  double base = (double)(32 << lvl);
  int si = a % 3, ri = a / 3;
  double s = (si == 0) ? 1.0 : (si == 1) ? 1.2599210498948731648 : 1.5874010519681994748;
  double ratio = (ri == 0) ? 0.5 : (ri == 1) ? 1.0 : 2.0;
  double ws0 = base * s;
  double area = ws0 * ws0;
  double w = sqrt(area / ratio);
  double h = w * ratio;
  double cx = ((double)x + 0.5) * stride;
  double cy = ((double)y + 0.5) * stride;
  float ax1 = (float)(cx - 0.5 * w);
  float ay1 = (float)(cy - 0.5 * h);
  float ax2 = (float)(cx + (w - 0.5 * w));
  float ay2 = (float)(cy + (h - 0.5 * h));
  float4 rg = ((const float4*)regs)[n];
  float aw = ax2 - ax1, ah = ay2 - ay1;
  float acx = ax1 + 0.5f * aw, acy = ay1 + 0.5f * ah;
  float pcx = acx + rg.x * 0.1f * aw;
  float pcy = acy + rg.y * 0.1f * ah;
  float pw = expf(rg.z * 0.2f) * aw;
  float ph = expf(rg.w * 0.2f) * ah;
  float x1 = pcx - 0.5f * pw, y1 = pcy - 0.5f * ph;
  float x2 = pcx + 0.5f * pw, y2 = pcy + 0.5f * ph;
  x1 = fminf(fmaxf(x1, 0.f), 640.f);
  y1 = fminf(fmaxf(y1, 0.f), 640.f);
  x2 = fminf(fmaxf(x2, 0.f), 640.f);
  y2 = fminf(fmaxf(y2, 0.f), 640.f);
  float sc = scores[n];
  if (sc > 0.05f) {
    int p = atomicAdd(&meta[0], 1);
    cand_s[p] = sc;
    cand_b[p] = make_float4(x1, y1, x2, y2);
    cand_n[p] = n;
    unsigned int sb = __float_as_uint(sc);
    int bk = (int)(sb >> 16) - (int)BBASE;
    bk = max(0, min(NBKT - 1, bk));
    atomicAdd(&meta[1 + bk], 1);
  }
}

// ---------------- sort-based exact greedy NMS (unchanged) ----------------
__global__ __launch_bounds__(512) void nms2_k(const float* __restrict__ cs,
                                              const float4* __restrict__ cb,
                                              const int* __restrict__ cn,
                                              const int* __restrict__ meta,
                                              float* __restrict__ out) {
  __shared__ unsigned long long skey[SORT_N];
  __shared__ int sidx[SORT_N];
  __shared__ int suf[NBKT];
  __shared__ float kx1[300], ky1[300], kx2[300], ky2[300], kar[300];
  __shared__ int sh_i[8];
  const int tid = threadIdx.x;
  const int m = min(meta[0], N_ANCH);

  for (int b = tid; b < NBKT; b += 512) suf[b] = meta[1 + b];
  __syncthreads();
  for (int off = 1; off < NBKT; off <<= 1) {
    int v[2];
    for (int q = 0, b = tid; b < NBKT; b += 512, q++)
      v[q] = suf[b] + ((b + off < NBKT) ? suf[b + off] : 0);
    __syncthreads();
    for (int q = 0, b = tid; b < NBKT; b += 512, q++) suf[b] = v[q];
    __syncthreads();
  }

  int nk = 0;
  unsigned long long hi64 = ~0ULL;
  int processed = 0;

  while (nk < 300 && processed < m) {
    int base = 0;
    if (hi64 != ~0ULL) {
      if (tid == 0) sh_i[4] = 0;
      __syncthreads();
      int c = 0;
      for (int j = tid; j < m; j += 512) {
        unsigned long long K = ((unsigned long long)__float_as_uint(cs[j]) << 32) |
                               (unsigned int)(~cn[j]);
        if (K >= hi64) c++;
      }
      atomicAdd(&sh_i[4], c);
      __syncthreads();
      base = sh_i[4];
      __syncthreads();
    }
    if (tid == 0) sh_i[3] = NBKT + 1;
    __syncthreads();
    for (int T = tid; T < NBKT; T += 512) {
      unsigned long long lo =
          (T == 0) ? 0ULL : ((unsigned long long)(((unsigned)T + BBASE) << 16) << 32);
      int c = suf[T] - base;
      if (lo < hi64 && c >= 1 && c <= SORT_N) atomicMin(&sh_i[3], T);
    }
    __syncthreads();
    int T = sh_i[3];
    __syncthreads();
    unsigned long long lo64;
    if (T <= NBKT) {
      lo64 = (T == 0) ? 0ULL : ((unsigned long long)(((unsigned)T + BBASE) << 16) << 32);
    } else {
      unsigned long long L = 0, H = hi64;
      while (H - L > 1) {
        unsigned long long mid = L + ((H - L) >> 1);
        if (tid == 0) sh_i[4] = 0;
        __syncthreads();
        int c = 0;
        for (int j = tid; j < m; j += 512) {
          unsigned long long K = ((unsigned long long)__float_as_uint(cs[j]) << 32) |
                                 (unsigned int)(~cn[j]);
          if (K >= mid && K < hi64) c++;
        }
        atomicAdd(&sh_i[4], c);
        __syncthreads();
        int cc = sh_i[4];
        __syncthreads();
        if (cc > SORT_N) L = mid; else H = mid;
      }
      lo64 = H;
    }
    if (tid == 0) sh_i[0] = 0;
    __syncthreads();
    for (int j = tid; j < m; j += 512) {
      unsigned long long K = ((unsigned long long)__float_as_uint(cs[j]) << 32) |
                             (unsigned int)(~cn[j]);
      if (K >= lo64 && K < hi64) {
        int p = atomicAdd(&sh_i[0], 1);
        if (p < SORT_N) { skey[p] = K; sidx[p] = j; }
      }
    }
    __syncthreads();
    int bn = min(sh_i[0], SORT_N);
    __syncthreads();
    for (int p = bn + tid; p < SORT_N; p += 512) { skey[p] = 0; sidx[p] = 0; }
    __syncthreads();
    for (int k = 2; k <= SORT_N; k <<= 1) {
      for (int jj = k >> 1; jj > 0; jj >>= 1) {
        for (int i = tid; i < SORT_N; i += 512) {
          int l = i ^ jj;
          if (l > i) {
            unsigned long long a = skey[i], b2 = skey[l];
            bool desc = ((i & k) == 0);
            if ((a < b2) == desc) {
              skey[i] = b2; skey[l] = a;
              int t2 = sidx[i]; sidx[i] = sidx[l]; sidx[l] = t2;
            }
          }
        }
        __syncthreads();
      }
    }
    float4 bc = (bn > 0) ? cb[sidx[0]] : make_float4(0.f, 0.f, 0.f, 0.f);
    int pos = 0;
    while (pos < bn && nk < 300) {
      float4 b = bc;
      unsigned long long K = skey[pos];
      if (pos + 1 < bn) bc = cb[sidx[pos + 1]];
      if (tid == 0) sh_i[1] = 0;
      __syncthreads();
      float ar = (b.z - b.x) * (b.w - b.y);
      if (tid < nk) {
        float xx1 = fmaxf(kx1[tid], b.x), yy1 = fmaxf(ky1[tid], b.y);
        float xx2 = fminf(kx2[tid], b.z), yy2 = fminf(ky2[tid], b.w);
        float inter = fmaxf(xx2 - xx1, 0.f) * fmaxf(yy2 - yy1, 0.f);
        float iou = inter / (ar + kar[tid] - inter + 1e-8f);
        if (iou > 0.5f) sh_i[1] = 1;
      }
      __syncthreads();
      int flag = sh_i[1];
      if (!flag) {
        if (tid == 0) {
          kx1[nk] = b.x; ky1[nk] = b.y; kx2[nk] = b.z; ky2[nk] = b.w; kar[nk] = ar;
          out[nk] = __uint_as_float((unsigned int)(K >> 32));
          out[300 + nk] = 0.0f;
          out[600 + 4 * nk + 0] = b.x;
          out[600 + 4 * nk + 1] = b.y;
          out[600 + 4 * nk + 2] = b.z;
          out[600 + 4 * nk + 3] = b.w;
        }
        nk++;
      }
      pos++;
      __syncthreads();
    }
    processed = base + bn;
    hi64 = lo64;
  }
  __syncthreads();
  for (int r = nk + tid; r < 300; r += 512) {
    out[r] = 0.f;
    out[300 + r] = -1.f;
    out[600 + 4 * r + 0] = 0.f;
    out[600 + 4 * r + 1] = 0.f;
    out[600 + 4 * r + 2] = 0.f;
    out[600 + 4 * r + 3] = 0.f;
  }
}

// ---------------- host ----------------
extern "C" void kernel_launch(void* const* d_in, const int* in_sizes, int n_in,
                              void* d_out, int out_size, void* d_ws, size_t ws_size,
                              hipStream_t stream) {
  (void)in_sizes; (void)n_in; (void)out_size; (void)ws_size;
  const float* feats[5];
  for (int l = 0; l < 5; l++) feats[l] = (const float*)d_in[1 + l];
  const float* cls_w = (const float*)d_in[6];
  const float* cls_b = (const float*)d_in[7];
  const float* cls_ow = (const float*)d_in[8];
  const float* cls_ob = (const float*)d_in[9];
  const float* reg_w = (const float*)d_in[10];
  const float* reg_b = (const float*)d_in[11];
  const float* reg_ow = (const float*)d_in[12];
  const float* reg_ob = (const float*)d_in[13];

  static const int AOFF[5] = {0, 1638400, 2048000, 2150400, 2176000}; // 256*cumHW
  const size_t ACT = 2182400;  // 256*8525 floats per head

  float* ws = (float*)d_ws;
  float* bufA = ws;                       // 2*ACT
  float* bufB = bufA + 2 * ACT;           // 2*ACT
  float* scores = bufB + 2 * ACT;         // 76736 (padded)
  float* regs = scores + 76736;           // 306912 (padded)
  float* cand_s = regs + 306912;          // 76736
  float* cand_b = cand_s + 76736;         // 306944
  int* cand_n = (int*)(cand_b + 306944);  // 76736 ints
  int* meta = cand_n + 76736;             // [0]=cnt, [1..NBKT]=hist

  float* bufs[2] = {bufA, bufB};
  TrunkArgs ta;
  for (int layer = 0; layer < 4; layer++) {
    for (int h = 0; h < 2; h++) {
      ta.w[h] = (h ? reg_w : cls_w) + (size_t)layer * 589824;
      ta.b[h] = (h ? reg_b : cls_b) + layer * 256;
      for (int l = 0; l < 5; l++) {
        ta.out[h][l] = bufs[layer & 1] + h * ACT + AOFF[l];
        ta.in[h][l] = (layer == 0) ? feats[l] : (const float*)(bufs[(layer - 1) & 1] + h * ACT + AOFF[l]);
      }
    }
    conv_trunk<<<dim3(139, 4, 2), dim3(256), 0, stream>>>(ta);
  }

  Out2Args oa;
  for (int l = 0; l < 5; l++) {
    oa.in[0][l] = bufB + 0 * ACT + AOFF[l];
    oa.in[1][l] = bufB + 1 * ACT + AOFF[l];
  }
  oa.w[0] = cls_ow; oa.w[1] = reg_ow;
  oa.b[0] = cls_ob; oa.b[1] = reg_ob;
  oa.dst[0] = scores; oa.dst[1] = regs;
  conv_out2<<<dim3(139, 5), dim3(192), 0, stream>>>(oa);

  init_k<<<dim3(5), dim3(256), 0, stream>>>(meta);
  decode_k<<<dim3((N_ANCH + 255) / 256), dim3(256), 0, stream>>>(scores, regs, cand_s,
                                                                 (float4*)cand_b, cand_n, meta);
  nms2_k<<<dim3(1), dim3(512), 0, stream>>>(cand_s, (const float4*)cand_b, cand_n, meta,
                                            (float*)d_out);
}

// Round 6
// 1977.647 us; speedup vs baseline: 2.6347x; 1.0008x over previous
//
#include <hip/hip_runtime.h>
#include <math.h>

#define N_ANCH 76725
#define SORT_N 4096
#define NBKT 1024
#define BBASE 0x3D40u

struct TrunkArgs {
  const float* in[2][5];
  float* out[2][5];
  const float* w[2];   // TRANSPOSED weights: wT[(ci*9+tap)*256 + co], per head
  const float* b[2];
};

struct WtrArgs {
  const float* src[2];  // original w[co][ci][tap] per head, one layer
  float* dst;           // wT, 2 heads x 2304 x 256
};

struct Out2Args {
  const float* in[2][5];  // [head][lvl]
  const float* w[2];      // cls_ow, reg_ow (original layout)
  const float* b[2];      // cls_ob, reg_ob
  float* dst[2];          // scores (per-anchor), regs (per-anchor x4)
};

__device__ __forceinline__ int pick5(int l, int a, int b, int c, int d, int e) {
  int r = a;
  if (l == 1) r = b;
  if (l == 2) r = c;
  if (l == 3) r = d;
  if (l == 4) r = e;
  return r;
}

// 64-position tiling (8x8), used by conv_out2: 139 tiles
__device__ __forceinline__ void tile_to_level(int tile, int& lvl, int& t) {
  int l = 0;
  if (tile >= 100) l = 1;
  if (tile >= 125) l = 2;
  if (tile >= 134) l = 3;
  if (tile >= 138) l = 4;
  lvl = l;
  t = tile - pick5(l, 0, 100, 125, 134, 138);
}

// ---------------- weight transpose: w[co][ci][tap] -> wT[(ci*9+tap)][co] ----------------
// one layer, both heads. LDS tile keeps both global phases coalesced.
__global__ __launch_bounds__(256) void wtr_k(WtrArgs a) {
  __shared__ float tile[72][65];
  const int r0 = blockIdx.x * 72;   // 32 groups
  const int co0 = blockIdx.y * 64;  // 4 groups
  const int head = blockIdx.z;
  const float* __restrict__ src = a.src[head];
  float* __restrict__ dst = a.dst + (size_t)head * 2304 * 256;
  const int tid = threadIdx.x;
  #pragma unroll
  for (int i = 0; i < 18; i++) {
    int e = tid + 256 * i;  // < 4608
    int co = e / 72;
    int r = e - co * 72;
    tile[r][co] = src[(size_t)(co0 + co) * 2304 + r0 + r];
  }
  __syncthreads();
  #pragma unroll
  for (int i = 0; i < 18; i++) {
    int e = tid + 256 * i;
    int r = e >> 6;
    int co = e & 63;
    dst[(size_t)(r0 + r) * 256 + co0 + co] = tile[r][co];
  }
}

// ---------------- trunk conv: 256->256, 3x3, SAME, ReLU ----------------
// block tile: 128 positions (16 rows x 8 cols) x 64 co, BK=8.
// thread tile: 8 pos (one row) x 4 co -> 16 FMA per LDS instr.
// Weights staged from transposed layout: float4 global + ds_write_b128,
// conflict-free. FMA order (ci asc, ty asc, tx asc) identical -> bit-exact.
__device__ __forceinline__ void ct_load(const float* __restrict__ in,
                                        const float* __restrict__ wt, int ci0,
                                        int ty0, int tx0, int W, int HW, int tid,
                                        float a_reg[6], float4 w_reg[5]) {
  const float* inc = in + ci0 * HW;
  #pragma unroll
  for (int i = 0; i < 6; i++) {
    int e = tid + 256 * i;
    float v = 0.f;
    if (e < 1440) {
      int ci = e / 180;
      int rem = e - ci * 180;
      int yy = rem / 10;
      int xx = rem - yy * 10;
      int gy = ty0 + yy - 1, gx = tx0 + xx - 1;
      if ((unsigned)gy < (unsigned)W && (unsigned)gx < (unsigned)W)
        v = inc[ci * HW + gy * W + gx];
    }
    a_reg[i] = v;
  }
  const float* wc = wt + (size_t)ci0 * 9 * 256;
  #pragma unroll
  for (int i = 0; i < 5; i++) {
    int e = tid + 256 * i;
    if (e < 1152) {
      int rr = e >> 4;
      int c4 = e & 15;
      w_reg[i] = *(const float4*)(wc + rr * 256 + 4 * c4);
    }
  }
}

__device__ __forceinline__ void ct_store(int tid, const float a_reg[6],
                                         const float4 w_reg[5],
                                         float As[8][18][12], float Ws[8][9][68]) {
  #pragma unroll
  for (int i = 0; i < 6; i++) {
    int e = tid + 256 * i;
    if (e < 1440) {
      int ci = e / 180;
      int rem = e - ci * 180;
      int yy = rem / 10;
      int xx = rem - yy * 10;
      As[ci][yy][xx] = a_reg[i];
    }
  }
  float* dst0 = &Ws[0][0][0];
  #pragma unroll
  for (int i = 0; i < 5; i++) {
    int e = tid + 256 * i;
    if (e < 1152) {
      int rr = e >> 4;
      int c4 = e & 15;
      *(float4*)(dst0 + rr * 68 + 4 * c4) = w_reg[i];  // lane-consecutive co: conflict-free
    }
  }
}

__global__ __launch_bounds__(256) void conv_trunk(TrunkArgs args) {
  __shared__ float As[8][18][12];   // rows padded to 12 (b128-aligned)
  __shared__ float Ws[8][9][68];
  // 128-pos tiling: offsets {0,50,65,71,73,74}
  int l = 0;
  if (blockIdx.x >= 50) l = 1;
  if (blockIdx.x >= 65) l = 2;
  if (blockIdx.x >= 71) l = 3;
  if (blockIdx.x >= 73) l = 4;
  const int lvl = l;
  const int t = blockIdx.x - pick5(l, 0, 50, 65, 71, 73);
  const int W = 80 >> lvl;
  const int HW = W * W;
  const int tX = (W + 7) >> 3;
  const int ty0 = (t / tX) * 16, tx0 = (t % tX) * 8;
  const int head = blockIdx.z;
  const int co0 = blockIdx.y << 6;
  const float* __restrict__ in = args.in[head][lvl];
  float* __restrict__ out = args.out[head][lvl];
  const float* __restrict__ wt = args.w[head] + co0;
  const int tid = threadIdx.x;
  const int cop = tid & 15;
  const int ry = tid >> 4;          // 0..15: row within tile
  const int co_sub = cop << 2;
  float acc[8][4] = {};
  float a_reg[6];
  float4 w_reg[5];

  ct_load(in, wt, 0, ty0, tx0, W, HW, tid, a_reg, w_reg);
  ct_store(tid, a_reg, w_reg, As, Ws);
  __syncthreads();

  for (int ci0 = 0; ci0 < 256; ci0 += 8) {
    const bool more = (ci0 + 8) < 256;
    if (more) ct_load(in, wt, ci0 + 8, ty0, tx0, W, HW, tid, a_reg, w_reg);
    #pragma unroll 2
    for (int ci = 0; ci < 8; ci++) {
      #pragma unroll
      for (int ty = 0; ty < 3; ty++) {
        const float* ar = &As[ci][ry + ty][0];
        float4 a0 = *(const float4*)ar;
        float4 a1 = *(const float4*)(ar + 4);
        float2 a2 = *(const float2*)(ar + 8);
        float a[10] = {a0.x, a0.y, a0.z, a0.w, a1.x, a1.y, a1.z, a1.w, a2.x, a2.y};
        #pragma unroll
        for (int tx = 0; tx < 3; tx++) {
          float4 wv = *(const float4*)&Ws[ci][ty * 3 + tx][co_sub];
          #pragma unroll
          for (int p = 0; p < 8; p++) {
            acc[p][0] = fmaf(a[tx + p], wv.x, acc[p][0]);
            acc[p][1] = fmaf(a[tx + p], wv.y, acc[p][1]);
            acc[p][2] = fmaf(a[tx + p], wv.z, acc[p][2]);
            acc[p][3] = fmaf(a[tx + p], wv.w, acc[p][3]);
          }
        }
      }
    }
    if (more) {
      __syncthreads();
      ct_store(tid, a_reg, w_reg, As, Ws);
      __syncthreads();
    }
  }
  const float4 bias = *(const float4*)&args.b[head][co0 + co_sub];
  const int oy = ty0 + ry;
  if (oy < W) {
    #pragma unroll
    for (int p = 0; p < 8; p++) {
      int ox = tx0 + p;
      if (ox < W) {
        int base = oy * W + ox;
        out[(co0 + co_sub + 0) * HW + base] = fmaxf(acc[p][0] + bias.x, 0.f);
        out[(co0 + co_sub + 1) * HW + base] = fmaxf(acc[p][1] + bias.y, 0.f);
        out[(co0 + co_sub + 2) * HW + base] = fmaxf(acc[p][2] + bias.z, 0.f);
        out[(co0 + co_sub + 3) * HW + base] = fmaxf(acc[p][3] + bias.w, 0.f);
      }
    }
  }
}

// ---------------- fused output convs (unchanged from R4) ----------------
__global__ __launch_bounds__(192) void conv_out2(Out2Args args) {
  __shared__ float As[8][10][12];
  __shared__ float Wg[8][9][12];
  int lvl, t;
  tile_to_level(blockIdx.x, lvl, t);
  const int g = blockIdx.y;
  const int head = (g == 0) ? 0 : 1;
  const int co0 = (g == 0) ? 0 : (g - 1) * 9;
  const int W = 80 >> lvl;
  const int HW = W * W;
  const int tX = (W + 7) >> 3;
  const int ty0 = (t / tX) * 8, tx0 = (t % tX) * 8;
  const float* __restrict__ in = args.in[head][lvl];
  const float* __restrict__ wp = args.w[head] + (size_t)co0 * 2304;
  const int tid = threadIdx.x;
  const int lane = tid & 63;
  const int wv = tid >> 6;
  const int y = lane >> 3, x = lane & 7;
  float acc0 = 0.f, acc1 = 0.f, acc2 = 0.f;

  for (int ci0 = 0; ci0 < 256; ci0 += 8) {
    __syncthreads();
    for (int e = tid; e < 800; e += 192) {
      int ci = e / 100;
      int rem = e - ci * 100;
      int yy = rem / 10;
      int xx = rem - yy * 10;
      int gy = ty0 + yy - 1, gx = tx0 + xx - 1;
      float v = 0.f;
      if ((unsigned)gy < (unsigned)W && (unsigned)gx < (unsigned)W)
        v = in[(ci0 + ci) * HW + gy * W + gx];
      As[ci][yy][xx] = v;
    }
    for (int e = tid; e < 648; e += 192) {
      int co = e / 72;
      int r = e - co * 72;
      int ci = r / 9;
      int tap = r - ci * 9;
      Wg[ci][tap][co] = wp[(size_t)co * 2304 + (size_t)ci0 * 9 + r];
    }
    __syncthreads();
    #pragma unroll 2
    for (int ci = 0; ci < 8; ci++) {
      #pragma unroll
      for (int ty = 0; ty < 3; ty++) {
        float a0 = As[ci][y + ty][x + 0];
        float a1 = As[ci][y + ty][x + 1];
        float a2 = As[ci][y + ty][x + 2];
        #pragma unroll
        for (int tx = 0; tx < 3; tx++) {
          float av = (tx == 0) ? a0 : (tx == 1) ? a1 : a2;
          const float* wr = &Wg[ci][ty * 3 + tx][3 * wv];
          acc0 = fmaf(av, wr[0], acc0);
          acc1 = fmaf(av, wr[1], acc1);
          acc2 = fmaf(av, wr[2], acc2);
        }
      }
    }
  }
  const int oy = ty0 + y, ox = tx0 + x;
  if (oy < W && ox < W) {
    const int cell = oy * W + ox;
    const int aoff = pick5(lvl, 0, 57600, 72000, 75600, 76500);
    float* dst = args.dst[head];
    const float* bias = args.b[head];
    #pragma unroll
    for (int c = 0; c < 3; c++) {
      int co = co0 + 3 * wv + c;
      float v = ((c == 0) ? acc0 : (c == 1) ? acc1 : acc2) + bias[co];
      if (head == 0) {
        v = 1.f / (1.f + expf(-v));
        dst[aoff + cell * 9 + co] = v;
      } else {
        dst[(size_t)aoff * 4 + cell * 36 + co] = v;
      }
    }
  }
}

// ---------------- init / decode (unchanged) ----------------
__global__ void init_k(int* meta) {
  int i = blockIdx.x * 256 + threadIdx.x;
  if (i < 1 + NBKT) meta[i] = 0;
}

__global__ __launch_bounds__(256) void decode_k(const float* __restrict__ scores,
                                                const float* __restrict__ regs,
                                                float* cand_s, float4* cand_b,
                                                int* cand_n, int* meta) {
  int n = blockIdx.x * 256 + threadIdx.x;
  if (n >= N_ANCH) return;
  int lvl = 0;
  if (n >= 57600) lvl = 1;
  if (n >= 72000) lvl = 2;
  if (n >= 75600) lvl = 3;
  if (n >= 76500) lvl = 4;
  const int aoff = pick5(lvl, 0, 57600, 72000, 75600, 76500);
  const int W = 80 >> lvl;
  int r = n - aoff;
  int a = r % 9;
  int cell = r / 9;
  int x = cell % W, y = cell / W;
  double stride = (double)(8 << lvl);
  double base = (double)(32 << lvl);
  int si = a % 3, ri = a / 3;
  double s = (si == 0) ? 1.0 : (si == 1) ? 1.2599210498948731648 : 1.5874010519681994748;
  double ratio = (ri == 0) ? 0.5 : (ri == 1) ? 1.0 : 2.0;
  double ws0 = base * s;
  double area = ws0 * ws0;
  double w = sqrt(area / ratio);
  double h = w * ratio;
  double cx = ((double)x + 0.5) * stride;
  double cy = ((double)y + 0.5) * stride;
  float ax1 = (float)(cx - 0.5 * w);
  float ay1 = (float)(cy - 0.5 * h);
  float ax2 = (float)(cx + (w - 0.5 * w));
  float ay2 = (float)(cy + (h - 0.5 * h));
  float4 rg = ((const float4*)regs)[n];
  float aw = ax2 - ax1, ah = ay2 - ay1;
  float acx = ax1 + 0.5f * aw, acy = ay1 + 0.5f * ah;
  float pcx = acx + rg.x * 0.1f * aw;
  float pcy = acy + rg.y * 0.1f * ah;
  float pw = expf(rg.z * 0.2f) * aw;
  float ph = expf(rg.w * 0.2f) * ah;
  float x1 = pcx - 0.5f * pw, y1 = pcy - 0.5f * ph;
  float x2 = pcx + 0.5f * pw, y2 = pcy + 0.5f * ph;
  x1 = fminf(fmaxf(x1, 0.f), 640.f);
  y1 = fminf(fmaxf(y1, 0.f), 640.f);
  x2 = fminf(fmaxf(x2, 0.f), 640.f);
  y2 = fminf(fmaxf(y2, 0.f), 640.f);
  float sc = scores[n];
  if (sc > 0.05f) {
    int p = atomicAdd(&meta[0], 1);
    cand_s[p] = sc;
    cand_b[p] = make_float4(x1, y1, x2, y2);
    cand_n[p] = n;
    unsigned int sb = __float_as_uint(sc);
    int bk = (int)(sb >> 16) - (int)BBASE;
    bk = max(0, min(NBKT - 1, bk));
    atomicAdd(&meta[1 + bk], 1);
  }
}

// ---------------- sort-based exact greedy NMS (unchanged) ----------------
__global__ __launch_bounds__(512) void nms2_k(const float* __restrict__ cs,
                                              const float4* __restrict__ cb,
                                              const int* __restrict__ cn,
                                              const int* __restrict__ meta,
                                              float* __restrict__ out) {
  __shared__ unsigned long long skey[SORT_N];
  __shared__ int sidx[SORT_N];
  __shared__ int suf[NBKT];
  __shared__ float kx1[300], ky1[300], kx2[300], ky2[300], kar[300];
  __shared__ int sh_i[8];
  const int tid = threadIdx.x;
  const int m = min(meta[0], N_ANCH);

  for (int b = tid; b < NBKT; b += 512) suf[b] = meta[1 + b];
  __syncthreads();
  for (int off = 1; off < NBKT; off <<= 1) {
    int v[2];
    for (int q = 0, b = tid; b < NBKT; b += 512, q++)
      v[q] = suf[b] + ((b + off < NBKT) ? suf[b + off] : 0);
    __syncthreads();
    for (int q = 0, b = tid; b < NBKT; b += 512, q++) suf[b] = v[q];
    __syncthreads();
  }

  int nk = 0;
  unsigned long long hi64 = ~0ULL;
  int processed = 0;

  while (nk < 300 && processed < m) {
    int base = 0;
    if (hi64 != ~0ULL) {
      if (tid == 0) sh_i[4] = 0;
      __syncthreads();
      int c = 0;
      for (int j = tid; j < m; j += 512) {
        unsigned long long K = ((unsigned long long)__float_as_uint(cs[j]) << 32) |
                               (unsigned int)(~cn[j]);
        if (K >= hi64) c++;
      }
      atomicAdd(&sh_i[4], c);
      __syncthreads();
      base = sh_i[4];
      __syncthreads();
    }
    if (tid == 0) sh_i[3] = NBKT + 1;
    __syncthreads();
    for (int T = tid; T < NBKT; T += 512) {
      unsigned long long lo =
          (T == 0) ? 0ULL : ((unsigned long long)(((unsigned)T + BBASE) << 16) << 32);
      int c = suf[T] - base;
      if (lo < hi64 && c >= 1 && c <= SORT_N) atomicMin(&sh_i[3], T);
    }
    __syncthreads();
    int T = sh_i[3];
    __syncthreads();
    unsigned long long lo64;
    if (T <= NBKT) {
      lo64 = (T == 0) ? 0ULL : ((unsigned long long)(((unsigned)T + BBASE) << 16) << 32);
    } else {
      unsigned long long L = 0, H = hi64;
      while (H - L > 1) {
        unsigned long long mid = L + ((H - L) >> 1);
        if (tid == 0) sh_i[4] = 0;
        __syncthreads();
        int c = 0;
        for (int j = tid; j < m; j += 512) {
          unsigned long long K = ((unsigned long long)__float_as_uint(cs[j]) << 32) |
                                 (unsigned int)(~cn[j]);
          if (K >= mid && K < hi64) c++;
        }
        atomicAdd(&sh_i[4], c);
        __syncthreads();
        int cc = sh_i[4];
        __syncthreads();
        if (cc > SORT_N) L = mid; else H = mid;
      }
      lo64 = H;
    }
    if (tid == 0) sh_i[0] = 0;
    __syncthreads();
    for (int j = tid; j < m; j += 512) {
      unsigned long long K = ((unsigned long long)__float_as_uint(cs[j]) << 32) |
                             (unsigned int)(~cn[j]);
      if (K >= lo64 && K < hi64) {
        int p = atomicAdd(&sh_i[0], 1);
        if (p < SORT_N) { skey[p] = K; sidx[p] = j; }
      }
    }
    __syncthreads();
    int bn = min(sh_i[0], SORT_N);
    __syncthreads();
    for (int p = bn + tid; p < SORT_N; p += 512) { skey[p] = 0; sidx[p] = 0; }
    __syncthreads();
    for (int k = 2; k <= SORT_N; k <<= 1) {
      for (int jj = k >> 1; jj > 0; jj >>= 1) {
        for (int i = tid; i < SORT_N; i += 512) {
          int l2 = i ^ jj;
          if (l2 > i) {
            unsigned long long a = skey[i], b2 = skey[l2];
            bool desc = ((i & k) == 0);
            if ((a < b2) == desc) {
              skey[i] = b2; skey[l2] = a;
              int t2 = sidx[i]; sidx[i] = sidx[l2]; sidx[l2] = t2;
            }
          }
        }
        __syncthreads();
      }
    }
    float4 bc = (bn > 0) ? cb[sidx[0]] : make_float4(0.f, 0.f, 0.f, 0.f);
    int pos = 0;
    while (pos < bn && nk < 300) {
      float4 b = bc;
      unsigned long long K = skey[pos];
      if (pos + 1 < bn) bc = cb[sidx[pos + 1]];
      if (tid == 0) sh_i[1] = 0;
      __syncthreads();
      float ar = (b.z - b.x) * (b.w - b.y);
      if (tid < nk) {
        float xx1 = fmaxf(kx1[tid], b.x), yy1 = fmaxf(ky1[tid], b.y);
        float xx2 = fminf(kx2[tid], b.z), yy2 = fminf(ky2[tid], b.w);
        float inter = fmaxf(xx2 - xx1, 0.f) * fmaxf(yy2 - yy1, 0.f);
        float iou = inter / (ar + kar[tid] - inter + 1e-8f);
        if (iou > 0.5f) sh_i[1] = 1;
      }
      __syncthreads();
      int flag = sh_i[1];
      if (!flag) {
        if (tid == 0) {
          kx1[nk] = b.x; ky1[nk] = b.y; kx2[nk] = b.z; ky2[nk] = b.w; kar[nk] = ar;
          out[nk] = __uint_as_float((unsigned int)(K >> 32));
          out[300 + nk] = 0.0f;
          out[600 + 4 * nk + 0] = b.x;
          out[600 + 4 * nk + 1] = b.y;
          out[600 + 4 * nk + 2] = b.z;
          out[600 + 4 * nk + 3] = b.w;
        }
        nk++;
      }
      pos++;
      __syncthreads();
    }
    processed = base + bn;
    hi64 = lo64;
  }
  __syncthreads();
  for (int r = nk + tid; r < 300; r += 512) {
    out[r] = 0.f;
    out[300 + r] = -1.f;
    out[600 + 4 * r + 0] = 0.f;
    out[600 + 4 * r + 1] = 0.f;
    out[600 + 4 * r + 2] = 0.f;
    out[600 + 4 * r + 3] = 0.f;
  }
}

// ---------------- host ----------------
extern "C" void kernel_launch(void* const* d_in, const int* in_sizes, int n_in,
                              void* d_out, int out_size, void* d_ws, size_t ws_size,
                              hipStream_t stream) {
  (void)in_sizes; (void)n_in; (void)out_size; (void)ws_size;
  const float* feats[5];
  for (int l = 0; l < 5; l++) feats[l] = (const float*)d_in[1 + l];
  const float* cls_w = (const float*)d_in[6];
  const float* cls_b = (const float*)d_in[7];
  const float* cls_ow = (const float*)d_in[8];
  const float* cls_ob = (const float*)d_in[9];
  const float* reg_w = (const float*)d_in[10];
  const float* reg_b = (const float*)d_in[11];
  const float* reg_ow = (const float*)d_in[12];
  const float* reg_ob = (const float*)d_in[13];

  static const int AOFF[5] = {0, 1638400, 2048000, 2150400, 2176000}; // 256*cumHW
  const size_t ACT = 2182400;  // 256*8525 floats per head

  float* ws = (float*)d_ws;
  float* bufA = ws;                       // 2*ACT
  float* bufB = bufA + 2 * ACT;           // 2*ACT
  float* scores = bufB + 2 * ACT;         // 76736 (padded)
  float* regs = scores + 76736;           // 306912 (padded)
  float* cand_s = regs + 306912;          // 76736
  float* cand_b = cand_s + 76736;         // 306944
  int* cand_n = (int*)(cand_b + 306944);  // 76736 ints
  int* meta = cand_n + 76736;             // [0]=cnt, [1..NBKT]=hist
  float* wt = (float*)(meta + 1032);      // 2*2304*256 floats (transposed wts, reused per layer)

  float* bufs[2] = {bufA, bufB};
  TrunkArgs ta;
  WtrArgs wa;
  wa.dst = wt;
  for (int layer = 0; layer < 4; layer++) {
    wa.src[0] = cls_w + (size_t)layer * 589824;
    wa.src[1] = reg_w + (size_t)layer * 589824;
    wtr_k<<<dim3(32, 4, 2), dim3(256), 0, stream>>>(wa);
    for (int h = 0; h < 2; h++) {
      ta.w[h] = wt + (size_t)h * 589824;  // 2304*256
      ta.b[h] = (h ? reg_b : cls_b) + layer * 256;
      for (int l = 0; l < 5; l++) {
        ta.out[h][l] = bufs[layer & 1] + h * ACT + AOFF[l];
        ta.in[h][l] = (layer == 0) ? feats[l] : (const float*)(bufs[(layer - 1) & 1] + h * ACT + AOFF[l]);
      }
    }
    conv_trunk<<<dim3(74, 4, 2), dim3(256), 0, stream>>>(ta);
  }

  Out2Args oa;
  for (int l = 0; l < 5; l++) {
    oa.in[0][l] = bufB + 0 * ACT + AOFF[l];
    oa.in[1][l] = bufB + 1 * ACT + AOFF[l];
  }
  oa.w[0] = cls_ow; oa.w[1] = reg_ow;
  oa.b[0] = cls_ob; oa.b[1] = reg_ob;
  oa.dst[0] = scores; oa.dst[1] = regs;
  conv_out2<<<dim3(139, 5), dim3(192), 0, stream>>>(oa);

  init_k<<<dim3(5), dim3(256), 0, stream>>>(meta);
  decode_k<<<dim3((N_ANCH + 255) / 256), dim3(256), 0, stream>>>(scores, regs, cand_s,
                                                                 (float4*)cand_b, cand_n, meta);
  nms2_k<<<dim3(1), dim3(512), 0, stream>>>(cand_s, (const float4*)cand_b, cand_n, meta,
                                            (float*)d_out);
}